// Round 8
// baseline (582.576 us; speedup 1.0000x reference)
//
#include <hip/hip_runtime.h>

#define DEVI __device__ __forceinline__

typedef __attribute__((ext_vector_type(8))) short s16x8;
typedef __attribute__((ext_vector_type(4))) float f32x4;
typedef __attribute__((ext_vector_type(4))) unsigned short u16x4;
typedef __attribute__((ext_vector_type(4))) int i32x4;

static constexpr int NB = 8;      // batch
static constexpr int NC = 1024;   // channels
static constexpr int NT = 1024;   // time
static constexpr int NH = 16;     // heads
static constexpr int ND = 64;     // head dim

DEVI unsigned short cvt_bf16(float f) {
  unsigned int u = __builtin_bit_cast(unsigned int, f);
  u += 0x7fffu + ((u >> 16) & 1u);
  return (unsigned short)(u >> 16);
}

DEVI float fexp2(float x) {
#if __has_builtin(__builtin_amdgcn_exp2f)
  return __builtin_amdgcn_exp2f(x);
#else
  return exp2f(x);
#endif
}

// Stage a ROWS x 64 bf16 tile (row-major global, ld elems/row) into LDS at byte
// offset loff. 128 B per LDS row. Linear LDS dest, XOR-16B-chunk swizzle applied
// on the GLOBAL source (m173 pattern). Issues exactly ROWS/32 VMEM ops/thread.
template<int ROWS>
DEVI void stage_tile(const unsigned short* g, int ld, char* lds, int loff, int tid) {
  const int wave = tid >> 6;
  const int lane = tid & 63;
#pragma unroll
  for (int r = 0; r < (ROWS >> 5); ++r) {
    const int row = r * 32 + wave * 8 + (lane >> 3);
    const int c  = lane & 7;
    const int cg = c ^ (row & 7);
    const char* src = (const char*)g + (size_t)row * ld * 2 + cg * 16;
    char* dst = lds + loff + (r * 32 + wave * 8) * 128;  // wave-uniform
    __builtin_amdgcn_global_load_lds((const __attribute__((address_space(1))) void*)src,
                                     (__attribute__((address_space(3))) void*)dst,
                                     16, 0, 0);
  }
}

// Stage V tile: 64 rows (d) x 128 cols (k) bf16, 256 B/row, 16 KB total.
// 16B-chunk index swizzled with ^(d&15) via pre-swizzled global source.
DEVI void stage_v(const unsigned short* v, int k0, char* lds, int loff, int tid) {
  const int wave = tid >> 6;
  const int lane = tid & 63;
#pragma unroll
  for (int it = 0; it < 4; ++it) {
    const int d = wave * 16 + it * 4 + (lane >> 4);
    const int c = lane & 15;
    const int cg = c ^ (d & 15);
    const char* src = (const char*)(v + (size_t)d * NT + k0 + cg * 8);
    char* dst = lds + loff + (wave * 16 + it * 4) * 256;  // wave-uniform, +lane*16 by HW
    __builtin_amdgcn_global_load_lds((const __attribute__((address_space(1))) void*)src,
                                     (__attribute__((address_space(3))) void*)dst,
                                     16, 0, 0);
  }
}

// Fragment read for mfma_f32_16x16x32_bf16: lane holds A[row][ks*32+(lane>>4)*8 .. +8]
DEVI s16x8 frag_ld(const char* lds, int loff, int row, int ks, int lane) {
  const int chunk = (ks * 4 + (lane >> 4)) ^ (row & 7);
  return *(const s16x8*)(lds + loff + row * 128 + chunk * 16);
}

// 128x128 tile TN GEMM core: A [M,K] rm, Bt [N,K] rm, both K-contiguous.
// 4 waves in 2x2, each wave 64x64 (4x4 fragments). lds must be >= 32768 B.
template<int KTOT>
DEVI void gemm_core_128(const unsigned short* A, const unsigned short* Bt,
                        int ldA, int ldB, char* lds, int tid, f32x4 acc[4][4]) {
  const int lane = tid & 63;
  const int wave = tid >> 6;
  const int wr = wave >> 1, wc = wave & 1;
#pragma unroll
  for (int i = 0; i < 4; ++i)
#pragma unroll
    for (int j = 0; j < 4; ++j)
      acc[i][j] = (f32x4){0.f, 0.f, 0.f, 0.f};
  for (int k0 = 0; k0 < KTOT; k0 += 64) {
    __syncthreads();
    stage_tile<128>(A + k0, ldA, lds, 0, tid);
    stage_tile<128>(Bt + k0, ldB, lds, 16384, tid);
    asm volatile("s_waitcnt vmcnt(0)" ::: "memory");
    __syncthreads();
#pragma unroll
    for (int ks = 0; ks < 2; ++ks) {
      s16x8 af[4], bfr[4];
#pragma unroll
      for (int mf = 0; mf < 4; ++mf)
        af[mf] = frag_ld(lds, 0, wr * 64 + mf * 16 + (lane & 15), ks, lane);
#pragma unroll
      for (int nf = 0; nf < 4; ++nf)
        bfr[nf] = frag_ld(lds, 16384, wc * 64 + nf * 16 + (lane & 15), ks, lane);
#pragma unroll
      for (int mf = 0; mf < 4; ++mf)
#pragma unroll
        for (int nf = 0; nf < 4; ++nf)
          acc[mf][nf] = __builtin_amdgcn_mfma_f32_16x16x32_bf16(af[mf], bfr[nf], acc[mf][nf], 0, 0, 0);
    }
  }
}

// ---------------- prep: both weight converts in one kernel ----------------
__global__ __launch_bounds__(256) void k_prep(const float* __restrict__ wkvq,
                                              unsigned short* __restrict__ wkvq_bf,
                                              const float* __restrict__ wout,
                                              unsigned short* __restrict__ wout_bf) {
  const int n1 = 3 * NC * NC / 4, n2 = NC * NC / 4;
  const int stride = gridDim.x * blockDim.x;
  for (int i = blockIdx.x * blockDim.x + threadIdx.x; i < n1 + n2; i += stride) {
    const float* src = (i < n1) ? wkvq + (size_t)i * 4 : wout + (size_t)(i - n1) * 4;
    unsigned short* dst = (i < n1) ? wkvq_bf + (size_t)i * 4 : wout_bf + (size_t)(i - n1) * 4;
    f32x4 v = *(const f32x4*)src;
    u16x4 o;
#pragma unroll
    for (int j = 0; j < 4; ++j) o[j] = cvt_bf16(v[j]);
    *(u16x4*)dst = o;
  }
}

// x [B,C,T] f32 -> xT [B,T,C] bf16
__global__ void k_xT(const float* __restrict__ x, unsigned short* __restrict__ xT) {
  __shared__ float tl[32][33];
  const int bz = blockIdx.z;
  const int t0 = blockIdx.x * 32, c0 = blockIdx.y * 32;
  const int tx = threadIdx.x, ty = threadIdx.y;  // (32,8)
#pragma unroll
  for (int j = 0; j < 4; ++j)
    tl[ty + j * 8][tx] = x[((size_t)bz * NC + c0 + ty + j * 8) * NT + t0 + tx];
  __syncthreads();
#pragma unroll
  for (int j = 0; j < 4; ++j)
    xT[((size_t)bz * NT + t0 + ty + j * 8) * NC + c0 + tx] = cvt_bf16(tl[tx][ty + j * 8]);
}

// ---------------- QKV projection: 256x256 tile, BK=32, 4-slot ring, counted vmcnt ----------------
__global__ __launch_bounds__(512, 2) void k_gemm1_256(const unsigned short* __restrict__ W,
                                                      const unsigned short* __restrict__ xT,
                                                      unsigned short* __restrict__ kt,
                                                      unsigned short* __restrict__ qt,
                                                      unsigned short* __restrict__ vbuf) {
  __shared__ char lds[131072];
  const int tid = threadIdx.x, lane = tid & 63, wid = tid >> 6;
  const int wr = wid >> 2, wc = wid & 3;
  // XCD-chunked bijective swizzle: 384 blocks = 8 XCDs x 48
  const int gid = blockIdx.x;
  const int wg = (gid & 7) * 48 + (gid >> 3);
  const int bn = wg / 12, bm = wg % 12;

  const int r = tid >> 2, ccc = tid & 3;
  const int cg = ccc ^ ((r ^ (r >> 2)) & 3);
  const unsigned short* srcA = W + (size_t)(bm * 256 + r) * NC + cg * 8;
  const unsigned short* srcB = xT + (size_t)(bn * 256 + r) * NC + cg * 8;

  auto stageA = [&](int t) {
    char* d = lds + (t & 3) * 32768 + wid * 1024;
    const unsigned short* s = srcA + t * 32;
    __builtin_amdgcn_global_load_lds((const __attribute__((address_space(1))) void*)s,
                                     (__attribute__((address_space(3))) void*)d, 16, 0, 0);
    __builtin_amdgcn_global_load_lds((const __attribute__((address_space(1))) void*)(s + 128 * NC),
                                     (__attribute__((address_space(3))) void*)(d + 8192), 16, 0, 0);
  };
  auto stageB = [&](int t) {
    char* d = lds + (t & 3) * 32768 + 16384 + wid * 1024;
    const unsigned short* s = srcB + t * 32;
    __builtin_amdgcn_global_load_lds((const __attribute__((address_space(1))) void*)s,
                                     (__attribute__((address_space(3))) void*)d, 16, 0, 0);
    __builtin_amdgcn_global_load_lds((const __attribute__((address_space(1))) void*)(s + 128 * NC),
                                     (__attribute__((address_space(3))) void*)(d + 8192), 16, 0, 0);
  };

  const int l15 = lane & 15, lg = lane >> 4;
  const int rA = wr * 128 + l15;
  const int offA = rA * 64 + (((lg ^ (rA ^ (rA >> 2))) & 3) << 4) + ((lg & ~3) << 4);
  const int rB = wc * 64 + l15;
  const int offB = 16384 + rB * 64 + (((lg ^ (rB ^ (rB >> 2))) & 3) << 4) + ((lg & ~3) << 4);

  f32x4 acc[8][4];
#pragma unroll
  for (int i = 0; i < 8; ++i)
#pragma unroll
    for (int j = 0; j < 4; ++j) acc[i][j] = (f32x4){0.f, 0.f, 0.f, 0.f};

  stageA(0); stageB(0); stageA(1); stageB(1); stageA(2); stageB(2);
  asm volatile("s_waitcnt vmcnt(8)" ::: "memory");   // slot 0 complete
  __builtin_amdgcn_s_barrier();

#pragma unroll
  for (int t = 0; t < 32; ++t) {
    const int slot = (t & 3) * 32768;
    s16x8 af[8], bf[4];
#pragma unroll
    for (int nf = 0; nf < 4; ++nf) bf[nf] = *(const s16x8*)(lds + slot + offB + nf * 1024);
#pragma unroll
    for (int mf = 0; mf < 4; ++mf) af[mf] = *(const s16x8*)(lds + slot + offA + mf * 1024);
    if (t < 29) stageA(t + 3);
    __builtin_amdgcn_s_barrier();
    asm volatile("s_waitcnt lgkmcnt(0)" ::: "memory");
    __builtin_amdgcn_sched_barrier(0);
    __builtin_amdgcn_s_setprio(1);
#pragma unroll
    for (int mf = 0; mf < 4; ++mf)
#pragma unroll
      for (int nf = 0; nf < 4; ++nf)
        acc[mf][nf] = __builtin_amdgcn_mfma_f32_16x16x32_bf16(af[mf], bf[nf], acc[mf][nf], 0, 0, 0);
    __builtin_amdgcn_s_setprio(0);
    __builtin_amdgcn_s_barrier();
#pragma unroll
    for (int mf = 4; mf < 8; ++mf) af[mf] = *(const s16x8*)(lds + slot + offA + mf * 1024);
    if (t < 29) stageB(t + 3);
    if (t < 29)       asm volatile("s_waitcnt vmcnt(8)" ::: "memory");  // slot t+1 ready
    else if (t == 29) asm volatile("s_waitcnt vmcnt(4)" ::: "memory");
    else              asm volatile("s_waitcnt vmcnt(0)" ::: "memory");
    __builtin_amdgcn_s_barrier();
    asm volatile("s_waitcnt lgkmcnt(0)" ::: "memory");
    __builtin_amdgcn_sched_barrier(0);
    __builtin_amdgcn_s_setprio(1);
#pragma unroll
    for (int mf = 4; mf < 8; ++mf)
#pragma unroll
      for (int nf = 0; nf < 4; ++nf)
        acc[mf][nf] = __builtin_amdgcn_mfma_f32_16x16x32_bf16(af[mf], bf[nf], acc[mf][nf], 0, 0, 0);
    __builtin_amdgcn_s_setprio(0);
    __builtin_amdgcn_s_barrier();
  }

  const int part = bm >> 2;           // 0=K 1=V 2=Q
  const int d0base = lg << 2;
#pragma unroll
  for (int mf = 0; mf < 8; ++mf) {
    const int h = ((bm & 3) << 2) + (wr << 1) + (mf >> 2);
    const int d0 = ((mf & 3) << 4) + d0base;
#pragma unroll
    for (int nf = 0; nf < 4; ++nf) {
      const int tg = bn * 256 + wc * 64 + nf * 16 + l15;
      const int b = tg >> 10, tt = tg & 1023;
      u16x4 v4;
#pragma unroll
      for (int i = 0; i < 4; ++i) v4[i] = cvt_bf16(acc[mf][nf][i]);
      if (part == 0) {
        *(u16x4*)(kt + (((size_t)(b * NH + h) * NT + tt) * ND + d0)) = v4;
      } else if (part == 1) {
        const size_t basev = ((size_t)(b * NH + h) * ND + d0) * NT + tt;
        vbuf[basev] = v4[0]; vbuf[basev + NT] = v4[1];
        vbuf[basev + 2 * NT] = v4[2]; vbuf[basev + 3 * NT] = v4[3];
      } else {
        *(u16x4*)(qt + (((size_t)(b * NH + h) * NT + tt) * ND + d0)) = v4;
      }
    }
  }
}

// ---------------- merged attention, swapped-QK layout ----------------
// (unchanged from r7; launched TWICE this round as a duration probe — the
// kernel is idempotent: pure function of kt/qt/vbuf/mask -> att/ctxT)
__global__ __launch_bounds__(256, 2) void k_att(const unsigned short* __restrict__ kt,
                                                const unsigned short* __restrict__ qt,
                                                const unsigned short* __restrict__ vbuf,
                                                const int* __restrict__ mask,
                                                float* __restrict__ att,
                                                unsigned short* __restrict__ ctxT) {
  __shared__ char lds[81920];
  constexpr int KOFF = 0, QOFF = 16384, VOFF = 32768, POFF = 49152;
  float* colacc = (float*)(lds + POFF);                    // pass-1 alias of P region
  unsigned long long* mbits = (unsigned long long*)(lds + POFF + 512);  // 16 u64
  const int tid = threadIdx.x, lane = tid & 63, wave = tid >> 6;
  const int wr = wave >> 1, wc = wave & 1;
  const int bh = blockIdx.x, qb = blockIdx.y;   // x=bh so q-replicas share an XCD
  const int b = bh >> 4, h = bh & 15, hb = h * NB + b;
  const int q0 = qb * 128;
  const unsigned short* ktp = kt + (size_t)bh * NT * ND;
  const unsigned short* qtp = qt + ((size_t)bh * NT + q0) * ND;
  const unsigned short* vp  = vbuf + (size_t)bh * ND * NT;
  const int l15 = lane & 15, g = lane >> 4;

  if (tid < 128) colacc[tid] = 0.f;
  stage_tile<128>(qtp, ND, lds, QOFF, tid);
  // k-mask bitset (wave w covers bits [w*256, w*256+256))
#pragma unroll
  for (int j = 0; j < 4; ++j) {
    unsigned long long bb = __ballot(mask[b * NT + wave * 256 + j * 64 + lane] != 0);
    if (lane == 0) mbits[wave * 4 + j] = bb;
  }
  // q-mask quad for this thread (4 consecutive q per nf)
  i32x4 qm4[4];
#pragma unroll
  for (int nf = 0; nf < 4; ++nf)
    qm4[nf] = *(const i32x4*)(mask + b * NT + q0 + wc * 64 + nf * 16 + g * 4);
  asm volatile("s_waitcnt vmcnt(0)" ::: "memory");
  __syncthreads();   // Q + mbits resident; vmcnt exactly 0

  s16x8 qf[4][2];
#pragma unroll
  for (int nf = 0; nf < 4; ++nf)
#pragma unroll
    for (int ks = 0; ks < 2; ++ks)
      qf[nf][ks] = frag_ld(lds, QOFF, wc * 64 + nf * 16 + l15, ks, lane);

  // per-thread k-mask bits: bit (t*4+mf) for k = t*128 + wr*64 + mf*16 + l15
  unsigned int kmask32 = 0;
#pragma unroll
  for (int t = 0; t < 8; ++t) {
    const unsigned long long w64 = mbits[t * 2 + wr];
#pragma unroll
    for (int mf = 0; mf < 4; ++mf)
      kmask32 |= (unsigned int)((w64 >> (mf * 16 + l15)) & 1ull) << (t * 4 + mf);
  }

  const float scl = 0.125f * 1.44269504f;  // scale * log2(e)

  // ---- pass 1: denominators (K double-buffered KOFF/VOFF, counted vmcnt(4)) ----
  f32x4 cs4[4];
#pragma unroll
  for (int nf = 0; nf < 4; ++nf) cs4[nf] = (f32x4){0.f, 0.f, 0.f, 0.f};
  stage_tile<128>(ktp, ND, lds, KOFF, tid);
  for (int t = 0; t < 8; ++t) {
    __builtin_amdgcn_s_barrier();
    if (t < 7) {
      stage_tile<128>(ktp + (size_t)(t + 1) * 128 * ND, ND, lds, (t & 1) ? KOFF : VOFF, tid);
      asm volatile("s_waitcnt vmcnt(4)" ::: "memory");
    } else {
      asm volatile("s_waitcnt vmcnt(0)" ::: "memory");
    }
    __builtin_amdgcn_s_barrier();
    const int koff = (t & 1) ? VOFF : KOFF;
    f32x4 sacc[4][4];
#pragma unroll
    for (int i = 0; i < 4; ++i)
#pragma unroll
      for (int j = 0; j < 4; ++j) sacc[i][j] = (f32x4){0.f, 0.f, 0.f, 0.f};
#pragma unroll
    for (int ks = 0; ks < 2; ++ks) {
      s16x8 kf[4];
#pragma unroll
      for (int mf = 0; mf < 4; ++mf)
        kf[mf] = frag_ld(lds, koff, wr * 64 + mf * 16 + l15, ks, lane);
#pragma unroll
      for (int mf = 0; mf < 4; ++mf)
#pragma unroll
        for (int nf = 0; nf < 4; ++nf)
          sacc[mf][nf] = __builtin_amdgcn_mfma_f32_16x16x32_bf16(qf[nf][ks], kf[mf], sacc[mf][nf], 0, 0, 0);
    }
#pragma unroll
    for (int mf = 0; mf < 4; ++mf) {
      const float kz = ((kmask32 >> (t * 4 + mf)) & 1u) ? 0.f : 1.f;
#pragma unroll
      for (int nf = 0; nf < 4; ++nf)
#pragma unroll
        for (int i = 0; i < 4; ++i)
          cs4[nf][i] += kz * fexp2(sacc[mf][nf][i] * scl);
    }
  }
  // reduce over 16 lanes (k) per group, then atomic-combine wr halves
#pragma unroll
  for (int nf = 0; nf < 4; ++nf)
#pragma unroll
    for (int i = 0; i < 4; ++i) {
      float v = cs4[nf][i];
      v += __shfl_xor(v, 1); v += __shfl_xor(v, 2);
      v += __shfl_xor(v, 4); v += __shfl_xor(v, 8);
      cs4[nf][i] = v;
    }
  if (l15 == 0) {
#pragma unroll
    for (int nf = 0; nf < 4; ++nf)
#pragma unroll
      for (int i = 0; i < 4; ++i)
        atomicAdd(&colacc[wc * 64 + nf * 16 + g * 4 + i], cs4[nf][i]);
  }
  __syncthreads();
  f32x4 sq4[4];
#pragma unroll
  for (int nf = 0; nf < 4; ++nf)
#pragma unroll
    for (int i = 0; i < 4; ++i)
      sq4[nf][i] = qm4[nf][i] ? 0.f : 1.0f / colacc[wc * 64 + nf * 16 + g * 4 + i];

  // ---- pass 2: att write + PV, stores never force-drained ----
  f32x4 cacc[4][2];
#pragma unroll
  for (int i = 0; i < 4; ++i)
#pragma unroll
    for (int j = 0; j < 2; ++j) cacc[i][j] = (f32x4){0.f, 0.f, 0.f, 0.f};

  stage_tile<128>(ktp, ND, lds, KOFF, tid);
  stage_v(vp, 0, lds, VOFF, tid);
  asm volatile("s_waitcnt vmcnt(0)" ::: "memory");
  __builtin_amdgcn_s_barrier();

  float* attb = att + (size_t)hb * NT * NT + q0 + wc * 64 + g * 4;
  for (int t = 0; t < 8; ++t) {
    // QK(t)
    f32x4 sacc[4][4];
#pragma unroll
    for (int i = 0; i < 4; ++i)
#pragma unroll
      for (int j = 0; j < 4; ++j) sacc[i][j] = (f32x4){0.f, 0.f, 0.f, 0.f};
#pragma unroll
    for (int ks = 0; ks < 2; ++ks) {
      s16x8 kf[4];
#pragma unroll
      for (int mf = 0; mf < 4; ++mf)
        kf[mf] = frag_ld(lds, KOFF, wr * 64 + mf * 16 + l15, ks, lane);
#pragma unroll
      for (int mf = 0; mf < 4; ++mf)
#pragma unroll
        for (int nf = 0; nf < 4; ++nf)
          sacc[mf][nf] = __builtin_amdgcn_mfma_f32_16x16x32_bf16(qf[nf][ks], kf[mf], sacc[mf][nf], 0, 0, 0);
    }
    __builtin_amdgcn_s_barrier();                 // KOFF free
    if (t < 7) stage_tile<128>(ktp + (size_t)(t + 1) * 128 * ND, ND, lds, KOFF, tid);
    __builtin_amdgcn_sched_barrier(0);            // pin: stageK before stores

    // epilogue: p4 = kz * exp * sq (dwordx4 att store) + P^T scalar bf16 -> LDS
#pragma unroll
    for (int mf = 0; mf < 4; ++mf) {
      const int kg = t * 128 + wr * 64 + mf * 16 + l15;
      const float kz = ((kmask32 >> (t * 4 + mf)) & 1u) ? 0.f : 1.f;
      const int kloc = wr * 64 + mf * 16 + l15;
#pragma unroll
      for (int nf = 0; nf < 4; ++nf) {
        f32x4 p4;
#pragma unroll
        for (int i = 0; i < 4; ++i)
          p4[i] = kz * fexp2(sacc[mf][nf][i] * scl) * sq4[nf][i];
        __builtin_nontemporal_store(p4, (f32x4*)(attb + (size_t)kg * NT + nf * 16));
        const int qrow = wc * 64 + nf * 16 + g * 4;
#pragma unroll
        for (int i = 0; i < 4; ++i) {
          const int row = qrow + i;
          *(unsigned short*)(lds + POFF + row * 256 + (((kloc >> 3) ^ (row & 15)) << 4)
                             + ((kloc & 7) << 1)) = cvt_bf16(p4[i]);
        }
      }
    }
    asm volatile("s_waitcnt lgkmcnt(0)" ::: "memory");  // P^T visible (NOT the att stores)
    __builtin_amdgcn_sched_barrier(0);
    __builtin_amdgcn_s_barrier();
    if (t > 0) {   // V(t) resident: retire stageV(t) (+ older stores(t-1)), keep stores(t)
      if (t < 7) asm volatile("s_waitcnt vmcnt(20)" ::: "memory");
      else       asm volatile("s_waitcnt vmcnt(16)" ::: "memory");
    }

    // PV(t): ctx[d][q] += V[d][k] * P[k][q]
#pragma unroll
    for (int ks2 = 0; ks2 < 4; ++ks2) {
      s16x8 vf[4], pf[2];
      const int chunk = (ks2 << 2) + g;
#pragma unroll
      for (int mf = 0; mf < 4; ++mf) {
        const int d = mf * 16 + l15;
        vf[mf] = *(const s16x8*)(lds + VOFF + d * 256 + ((chunk ^ (d & 15)) << 4));
      }
#pragma unroll
      for (int nf2 = 0; nf2 < 2; ++nf2) {
        const int qloc = wave * 32 + nf2 * 16 + l15;
        pf[nf2] = *(const s16x8*)(lds + POFF + qloc * 256 + ((chunk ^ (qloc & 15)) << 4));
      }
#pragma unroll
      for (int mf = 0; mf < 4; ++mf)
#pragma unroll
        for (int nf2 = 0; nf2 < 2; ++nf2)
          cacc[mf][nf2] = __builtin_amdgcn_mfma_f32_16x16x32_bf16(vf[mf], pf[nf2], cacc[mf][nf2], 0, 0, 0);
    }
    __builtin_amdgcn_s_barrier();                 // VOFF/POFF free
    if (t < 7) {
      stage_v(vp, (t + 1) * 128, lds, VOFF, tid);
      asm volatile("s_waitcnt vmcnt(20)" ::: "memory");  // K(t+1) resident
      __builtin_amdgcn_s_barrier();
    }
  }

  // ctx epilogue: ctxT[b][q][h*64+d]
#pragma unroll
  for (int mf = 0; mf < 4; ++mf) {
    const int d0 = mf * 16 + (g << 2);
#pragma unroll
    for (int nf2 = 0; nf2 < 2; ++nf2) {
      const int q = q0 + wave * 32 + nf2 * 16 + l15;
      u16x4 v4;
#pragma unroll
      for (int i = 0; i < 4; ++i) v4[i] = cvt_bf16(cacc[mf][nf2][i]);
      *(u16x4*)(ctxT + ((size_t)b * NT + q) * NC + h * ND + d0) = v4;
    }
  }
}

// ---------------- out-projection + residual + GN partial sums (128², full chip) ----------------
__global__ __launch_bounds__(256) void k_outgemm(const unsigned short* __restrict__ Wo,
                                                 const unsigned short* __restrict__ ctxT,
                                                 const float* __restrict__ x,
                                                 float* __restrict__ y0,
                                                 float* __restrict__ partials) {
  __shared__ char lds[32832];
  const int tid = threadIdx.x, lane = tid & 63, wave = tid >> 6;
  const int wr = wave >> 1, wc = wave & 1;
  const int bm = blockIdx.x, bn = blockIdx.y, b = blockIdx.z;
  const unsigned short* A = Wo + (size_t)bm * 128 * NC;
  const unsigned short* Bt = ctxT + ((size_t)b * NT + (size_t)bn * 128) * NC;
  f32x4 acc[4][4];
  gemm_core_128<NC>(A, Bt, NC, NC, lds, tid, acc);

  float lsum = 0.f, lsq = 0.f;
#pragma unroll
  for (int mf = 0; mf < 4; ++mf) {
#pragma unroll
    for (int nf = 0; nf < 4; ++nf) {
      const int gc = bn * 128 + wc * 64 + nf * 16 + (lane & 15);
#pragma unroll
      for (int i = 0; i < 4; ++i) {
        const int gr = bm * 128 + wr * 64 + mf * 16 + ((lane >> 4) << 2) + i;
        const size_t idx = ((size_t)b * NC + gr) * NT + gc;
        const float v = acc[mf][nf][i] + x[idx];
        y0[idx] = v;
        lsum += v; lsq += v * v;
      }
    }
  }
#pragma unroll
  for (int off = 32; off; off >>= 1) {
    lsum += __shfl_xor(lsum, off);
    lsq += __shfl_xor(lsq, off);
  }
  __syncthreads();
  float* red = (float*)(lds + 32768);
  if (lane == 0) { red[wave * 2] = lsum; red[wave * 2 + 1] = lsq; }
  __syncthreads();
  if (tid == 0) {
    const float s = red[0] + red[2] + red[4] + red[6];
    const float qq = red[1] + red[3] + red[5] + red[7];
    const int bi = bm * 8 + bn;
    partials[((size_t)b * 64 + bi) * 2] = s;
    partials[((size_t)b * 64 + bi) * 2 + 1] = qq;
  }
}

__global__ void k_gnstats(const float* __restrict__ partials, float* __restrict__ gnp) {
  const int b = blockIdx.x, t = threadIdx.x;  // 64 threads = 1 wave
  float s = partials[((size_t)b * 64 + t) * 2];
  float q = partials[((size_t)b * 64 + t) * 2 + 1];
#pragma unroll
  for (int off = 32; off; off >>= 1) {
    s += __shfl_xor(s, off);
    q += __shfl_xor(q, off);
  }
  if (t == 0) {
    const float n = 1048576.f;
    const float mean = s / n;
    const float var = q / n - mean * mean;
    gnp[b * 2] = mean;
    gnp[b * 2 + 1] = rsqrtf(var + 1e-5f);
  }
}

__global__ __launch_bounds__(256) void k_gnapply(const float* __restrict__ y0,
                                                 const float* __restrict__ gnp,
                                                 const float* __restrict__ gw,
                                                 const float* __restrict__ gb,
                                                 float* __restrict__ out) {
  const size_t n4 = (size_t)NB * NC * NT / 4;
  const size_t stride = (size_t)gridDim.x * blockDim.x;
  for (size_t i = (size_t)blockIdx.x * blockDim.x + threadIdx.x; i < n4; i += stride) {
    const size_t base = i * 4;
    const int b = (int)(base >> 20);
    const int c = (int)((base >> 10) & 1023);
    const f32x4 v = *(const f32x4*)(y0 + base);
    const float m = gnp[b * 2], r = gnp[b * 2 + 1];
    const float sw = gw[c] * r, sb = gb[c];
    f32x4 o;
#pragma unroll
    for (int j = 0; j < 4; ++j) o[j] = (v[j] - m) * sw + sb;
    *(f32x4*)(out + base) = o;
  }
}

extern "C" void kernel_launch(void* const* d_in, const int* in_sizes, int n_in,
                              void* d_out, int out_size, void* d_ws, size_t ws_size,
                              hipStream_t stream) {
  (void)in_sizes; (void)n_in; (void)out_size; (void)ws_size;
  const float* x     = (const float*)d_in[0];
  const int*   mask  = (const int*)d_in[1];
  const float* w_kvq = (const float*)d_in[2];
  const float* w_out = (const float*)d_in[3];
  const float* gnw   = (const float*)d_in[4];
  const float* gnb   = (const float*)d_in[5];
  float* outy = (float*)d_out;
  float* att  = outy + (size_t)NB * NC * NT;  // att_ret region of d_out

  char* ws = (char*)d_ws;
  unsigned short* wkvq_bf = (unsigned short*)(ws);             //  6,291,456 B
  unsigned short* wout_bf = (unsigned short*)(ws + 6291456);   //  2,097,152 B
  unsigned short* xT      = (unsigned short*)(ws + 8388608);   // 16,777,216 B
  unsigned short* ctxT    = xT;                                // alias: xT dead after gemm1
  unsigned short* kt      = (unsigned short*)(ws + 25165824);  // 16,777,216 B
  unsigned short* qt      = (unsigned short*)(ws + 41943040);  // 16,777,216 B
  float*          y0      = (float*)(ws + 25165824);           // alias kt+qt: dead after att
  unsigned short* vbuf    = (unsigned short*)(ws + 58720256);  // 16,777,216 B
  float*          part    = (float*)(ws + 76021760);           //      4,096 B
  float*          gnp     = (float*)(ws + 76025856);           //         64 B

  k_prep<<<2048, 256, 0, stream>>>(w_kvq, wkvq_bf, w_out, wout_bf);
  k_xT<<<dim3(32, 32, 8), dim3(32, 8), 0, stream>>>(x, xT);
  k_gemm1_256<<<384, 512, 0, stream>>>(wkvq_bf, xT, kt, qt, vbuf);
  // PROBE: k_att launched twice (idempotent). dur_us - 346.6 == T(k_att).
  k_att<<<dim3(128, 8), 256, 0, stream>>>(kt, qt, vbuf, mask, att, ctxT);
  k_att<<<dim3(128, 8), 256, 0, stream>>>(kt, qt, vbuf, mask, att, ctxT);
  k_outgemm<<<dim3(8, 8, 8), 256, 0, stream>>>(wout_bf, ctxT, x, y0, part);
  k_gnstats<<<8, 64, 0, stream>>>(part, gnp);
  k_gnapply<<<4096, 256, 0, stream>>>(y0, gnp, gnw, gnb, outy);
}

// Round 9
// 414.627 us; speedup vs baseline: 1.4051x; 1.4051x over previous
//
#include <hip/hip_runtime.h>

#define DEVI __device__ __forceinline__

typedef __attribute__((ext_vector_type(8))) short s16x8;
typedef __attribute__((ext_vector_type(4))) float f32x4;
typedef __attribute__((ext_vector_type(4))) unsigned short u16x4;
typedef __attribute__((ext_vector_type(4))) int i32x4;

static constexpr int NB = 8;      // batch
static constexpr int NC = 1024;   // channels
static constexpr int NT = 1024;   // time
static constexpr int NH = 16;     // heads
static constexpr int ND = 64;     // head dim

DEVI unsigned short cvt_bf16(float f) {
  unsigned int u = __builtin_bit_cast(unsigned int, f);
  u += 0x7fffu + ((u >> 16) & 1u);
  return (unsigned short)(u >> 16);
}

DEVI float bf16_to_f32(unsigned short s) {
  unsigned int u = (unsigned int)s << 16;
  return __builtin_bit_cast(float, u);
}

DEVI float fexp2(float x) {
#if __has_builtin(__builtin_amdgcn_exp2f)
  return __builtin_amdgcn_exp2f(x);
#else
  return exp2f(x);
#endif
}

// ---- 256-thread stager (used by gemm_core_128) ----
template<int ROWS>
DEVI void stage_tile(const unsigned short* g, int ld, char* lds, int loff, int tid) {
  const int wave = tid >> 6;
  const int lane = tid & 63;
#pragma unroll
  for (int r = 0; r < (ROWS >> 5); ++r) {
    const int row = r * 32 + wave * 8 + (lane >> 3);
    const int c  = lane & 7;
    const int cg = c ^ (row & 7);
    const char* src = (const char*)g + (size_t)row * ld * 2 + cg * 16;
    char* dst = lds + loff + (r * 32 + wave * 8) * 128;  // wave-uniform
    __builtin_amdgcn_global_load_lds((const __attribute__((address_space(1))) void*)src,
                                     (__attribute__((address_space(3))) void*)dst,
                                     16, 0, 0);
  }
}

// ---- 512-thread stagers for k_att2 ----
// 128 rows x 64 bf16 (128B/row), chunk swizzle c ^ (row&7). 2 VMEM ops/thread.
DEVI void stage_k512(const unsigned short* g, char* lds, int loff, int tid) {
  const int wave = tid >> 6, lane = tid & 63;
#pragma unroll
  for (int r = 0; r < 2; ++r) {
    const int row = r * 64 + wave * 8 + (lane >> 3);
    const int c = lane & 7, cg = c ^ (row & 7);
    const char* src = (const char*)g + (size_t)row * 128 + cg * 16;
    char* dst = lds + loff + (r * 64 + wave * 8) * 128;
    __builtin_amdgcn_global_load_lds((const __attribute__((address_space(1))) void*)src,
                                     (__attribute__((address_space(3))) void*)dst,
                                     16, 0, 0);
  }
}
// V: 64 rows (d) x 128 bf16 (256B/row), chunk swizzle c ^ (d&15). 2 VMEM ops/thread.
DEVI void stage_v512(const unsigned short* v, int k0, char* lds, int loff, int tid) {
  const int wave = tid >> 6, lane = tid & 63;
#pragma unroll
  for (int r = 0; r < 2; ++r) {
    const int d = r * 32 + wave * 4 + (lane >> 4);
    const int c = lane & 15, cg = c ^ (d & 15);
    const char* src = (const char*)(v + (size_t)d * NT + k0 + cg * 8);
    char* dst = lds + loff + (r * 32 + wave * 4) * 256;
    __builtin_amdgcn_global_load_lds((const __attribute__((address_space(1))) void*)src,
                                     (__attribute__((address_space(3))) void*)dst,
                                     16, 0, 0);
  }
}

// Fragment read for mfma_f32_16x16x32_bf16: lane holds A[row][ks*32+(lane>>4)*8 .. +8]
DEVI s16x8 frag_ld(const char* lds, int loff, int row, int ks, int lane) {
  const int chunk = (ks * 4 + (lane >> 4)) ^ (row & 7);
  return *(const s16x8*)(lds + loff + row * 128 + chunk * 16);
}

// 128x128 tile TN GEMM core (256 threads)
template<int KTOT>
DEVI void gemm_core_128(const unsigned short* A, const unsigned short* Bt,
                        int ldA, int ldB, char* lds, int tid, f32x4 acc[4][4]) {
  const int lane = tid & 63;
  const int wave = tid >> 6;
  const int wr = wave >> 1, wc = wave & 1;
#pragma unroll
  for (int i = 0; i < 4; ++i)
#pragma unroll
    for (int j = 0; j < 4; ++j)
      acc[i][j] = (f32x4){0.f, 0.f, 0.f, 0.f};
  for (int k0 = 0; k0 < KTOT; k0 += 64) {
    __syncthreads();
    stage_tile<128>(A + k0, ldA, lds, 0, tid);
    stage_tile<128>(Bt + k0, ldB, lds, 16384, tid);
    asm volatile("s_waitcnt vmcnt(0)" ::: "memory");
    __syncthreads();
#pragma unroll
    for (int ks = 0; ks < 2; ++ks) {
      s16x8 af[4], bfr[4];
#pragma unroll
      for (int mf = 0; mf < 4; ++mf)
        af[mf] = frag_ld(lds, 0, wr * 64 + mf * 16 + (lane & 15), ks, lane);
#pragma unroll
      for (int nf = 0; nf < 4; ++nf)
        bfr[nf] = frag_ld(lds, 16384, wc * 64 + nf * 16 + (lane & 15), ks, lane);
#pragma unroll
      for (int mf = 0; mf < 4; ++mf)
#pragma unroll
        for (int nf = 0; nf < 4; ++nf)
          acc[mf][nf] = __builtin_amdgcn_mfma_f32_16x16x32_bf16(af[mf], bfr[nf], acc[mf][nf], 0, 0, 0);
    }
  }
}

// ---------------- prep ----------------
__global__ __launch_bounds__(256) void k_prep(const float* __restrict__ wkvq,
                                              unsigned short* __restrict__ wkvq_bf,
                                              const float* __restrict__ wout,
                                              unsigned short* __restrict__ wout_bf) {
  const int n1 = 3 * NC * NC / 4, n2 = NC * NC / 4;
  const int stride = gridDim.x * blockDim.x;
  for (int i = blockIdx.x * blockDim.x + threadIdx.x; i < n1 + n2; i += stride) {
    const float* src = (i < n1) ? wkvq + (size_t)i * 4 : wout + (size_t)(i - n1) * 4;
    unsigned short* dst = (i < n1) ? wkvq_bf + (size_t)i * 4 : wout_bf + (size_t)(i - n1) * 4;
    f32x4 v = *(const f32x4*)src;
    u16x4 o;
#pragma unroll
    for (int j = 0; j < 4; ++j) o[j] = cvt_bf16(v[j]);
    *(u16x4*)dst = o;
  }
}

// x [B,C,T] f32 -> xT [B,T,C] bf16
__global__ void k_xT(const float* __restrict__ x, unsigned short* __restrict__ xT) {
  __shared__ float tl[32][33];
  const int bz = blockIdx.z;
  const int t0 = blockIdx.x * 32, c0 = blockIdx.y * 32;
  const int tx = threadIdx.x, ty = threadIdx.y;  // (32,8)
#pragma unroll
  for (int j = 0; j < 4; ++j)
    tl[ty + j * 8][tx] = x[((size_t)bz * NC + c0 + ty + j * 8) * NT + t0 + tx];
  __syncthreads();
#pragma unroll
  for (int j = 0; j < 4; ++j)
    xT[((size_t)bz * NT + t0 + ty + j * 8) * NC + c0 + tx] = cvt_bf16(tl[tx][ty + j * 8]);
}

// ---------------- QKV projection: 256x256 tile, BK=32, 4-slot ring, counted vmcnt ----------------
__global__ __launch_bounds__(512, 2) void k_gemm1_256(const unsigned short* __restrict__ W,
                                                      const unsigned short* __restrict__ xT,
                                                      unsigned short* __restrict__ kt,
                                                      unsigned short* __restrict__ qt,
                                                      unsigned short* __restrict__ vbuf) {
  __shared__ char lds[131072];
  const int tid = threadIdx.x, lane = tid & 63, wid = tid >> 6;
  const int wr = wid >> 2, wc = wid & 3;
  const int gid = blockIdx.x;
  const int wg = (gid & 7) * 48 + (gid >> 3);
  const int bn = wg / 12, bm = wg % 12;

  const int r = tid >> 2, ccc = tid & 3;
  const int cg = ccc ^ ((r ^ (r >> 2)) & 3);
  const unsigned short* srcA = W + (size_t)(bm * 256 + r) * NC + cg * 8;
  const unsigned short* srcB = xT + (size_t)(bn * 256 + r) * NC + cg * 8;

  auto stageA = [&](int t) {
    char* d = lds + (t & 3) * 32768 + wid * 1024;
    const unsigned short* s = srcA + t * 32;
    __builtin_amdgcn_global_load_lds((const __attribute__((address_space(1))) void*)s,
                                     (__attribute__((address_space(3))) void*)d, 16, 0, 0);
    __builtin_amdgcn_global_load_lds((const __attribute__((address_space(1))) void*)(s + 128 * NC),
                                     (__attribute__((address_space(3))) void*)(d + 8192), 16, 0, 0);
  };
  auto stageB = [&](int t) {
    char* d = lds + (t & 3) * 32768 + 16384 + wid * 1024;
    const unsigned short* s = srcB + t * 32;
    __builtin_amdgcn_global_load_lds((const __attribute__((address_space(1))) void*)s,
                                     (__attribute__((address_space(3))) void*)d, 16, 0, 0);
    __builtin_amdgcn_global_load_lds((const __attribute__((address_space(1))) void*)(s + 128 * NC),
                                     (__attribute__((address_space(3))) void*)(d + 8192), 16, 0, 0);
  };

  const int l15 = lane & 15, lg = lane >> 4;
  const int rA = wr * 128 + l15;
  const int offA = rA * 64 + (((lg ^ (rA ^ (rA >> 2))) & 3) << 4) + ((lg & ~3) << 4);
  const int rB = wc * 64 + l15;
  const int offB = 16384 + rB * 64 + (((lg ^ (rB ^ (rB >> 2))) & 3) << 4) + ((lg & ~3) << 4);

  f32x4 acc[8][4];
#pragma unroll
  for (int i = 0; i < 8; ++i)
#pragma unroll
    for (int j = 0; j < 4; ++j) acc[i][j] = (f32x4){0.f, 0.f, 0.f, 0.f};

  stageA(0); stageB(0); stageA(1); stageB(1); stageA(2); stageB(2);
  asm volatile("s_waitcnt vmcnt(8)" ::: "memory");
  __builtin_amdgcn_s_barrier();

#pragma unroll
  for (int t = 0; t < 32; ++t) {
    const int slot = (t & 3) * 32768;
    s16x8 af[8], bf[4];
#pragma unroll
    for (int nf = 0; nf < 4; ++nf) bf[nf] = *(const s16x8*)(lds + slot + offB + nf * 1024);
#pragma unroll
    for (int mf = 0; mf < 4; ++mf) af[mf] = *(const s16x8*)(lds + slot + offA + mf * 1024);
    if (t < 29) stageA(t + 3);
    __builtin_amdgcn_s_barrier();
    asm volatile("s_waitcnt lgkmcnt(0)" ::: "memory");
    __builtin_amdgcn_sched_barrier(0);
    __builtin_amdgcn_s_setprio(1);
#pragma unroll
    for (int mf = 0; mf < 4; ++mf)
#pragma unroll
      for (int nf = 0; nf < 4; ++nf)
        acc[mf][nf] = __builtin_amdgcn_mfma_f32_16x16x32_bf16(af[mf], bf[nf], acc[mf][nf], 0, 0, 0);
    __builtin_amdgcn_s_setprio(0);
    __builtin_amdgcn_s_barrier();
#pragma unroll
    for (int mf = 4; mf < 8; ++mf) af[mf] = *(const s16x8*)(lds + slot + offA + mf * 1024);
    if (t < 29) stageB(t + 3);
    if (t < 29)       asm volatile("s_waitcnt vmcnt(8)" ::: "memory");
    else if (t == 29) asm volatile("s_waitcnt vmcnt(4)" ::: "memory");
    else              asm volatile("s_waitcnt vmcnt(0)" ::: "memory");
    __builtin_amdgcn_s_barrier();
    asm volatile("s_waitcnt lgkmcnt(0)" ::: "memory");
    __builtin_amdgcn_sched_barrier(0);
    __builtin_amdgcn_s_setprio(1);
#pragma unroll
    for (int mf = 4; mf < 8; ++mf)
#pragma unroll
      for (int nf = 0; nf < 4; ++nf)
        acc[mf][nf] = __builtin_amdgcn_mfma_f32_16x16x32_bf16(af[mf], bf[nf], acc[mf][nf], 0, 0, 0);
    __builtin_amdgcn_s_setprio(0);
    __builtin_amdgcn_s_barrier();
  }

  const int part = bm >> 2;
  const int d0base = lg << 2;
#pragma unroll
  for (int mf = 0; mf < 8; ++mf) {
    const int h = ((bm & 3) << 2) + (wr << 1) + (mf >> 2);
    const int d0 = ((mf & 3) << 4) + d0base;
#pragma unroll
    for (int nf = 0; nf < 4; ++nf) {
      const int tg = bn * 256 + wc * 64 + nf * 16 + l15;
      const int b = tg >> 10, tt = tg & 1023;
      u16x4 v4;
#pragma unroll
      for (int i = 0; i < 4; ++i) v4[i] = cvt_bf16(acc[mf][nf][i]);
      if (part == 0) {
        *(u16x4*)(kt + (((size_t)(b * NH + h) * NT + tt) * ND + d0)) = v4;
      } else if (part == 1) {
        const size_t basev = ((size_t)(b * NH + h) * ND + d0) * NT + tt;
        vbuf[basev] = v4[0]; vbuf[basev + NT] = v4[1];
        vbuf[basev + 2 * NT] = v4[2]; vbuf[basev + 3 * NT] = v4[3];
      } else {
        *(u16x4*)(qt + (((size_t)(b * NH + h) * NT + tt) * ND + d0)) = v4;
      }
    }
  }
}

// ---------------- attention: SINGLE QK^T pass ----------------
// 512 threads (8 waves: wr=wid>>2 k-half, wc=wid&3 q-quarter), q-tile 128, 1 block/CU.
// Phase A: per k-tile (K,V dbuf, counted vmcnt): QK once -> exp once -> pack bf16 P
//   into registers (preg, unnormalized) -> colsum f32 accum -> relay raw P via LDS
//   -> PV accumulates UNNORMALIZED ctx (exact: ctx_norm = ctx_unnorm / colsum).
// Phase B: colsum reduce -> sq; ctx epilogue scaled by sq.
// Phase C: pure att store sweep (preg * sq), no barriers/LDS/waits.
__global__ __launch_bounds__(512, 1) void k_att2(const unsigned short* __restrict__ kt,
                                                 const unsigned short* __restrict__ qt,
                                                 const unsigned short* __restrict__ vbuf,
                                                 const int* __restrict__ mask,
                                                 float* __restrict__ att,
                                                 unsigned short* __restrict__ ctxT) {
  __shared__ char lds[115456];
  constexpr int QOFF = 0, KOFF0 = 16384, KOFF1 = 32768, VOFF0 = 49152, VOFF1 = 65536;
  constexpr int POFF = 81920, COFF = 114688;
  float* colacc = (float*)(lds + COFF);                      // 128 f32
  unsigned long long* mbits = (unsigned long long*)(lds + COFF + 512);  // 16 u64
  const int tid = threadIdx.x, lane = tid & 63, wid = tid >> 6;
  const int wr = wid >> 2, wc = wid & 3;
  const int bh = blockIdx.x, qb = blockIdx.y;   // x=bh so q-replicas share an XCD
  const int b = bh >> 4, h = bh & 15, hb = h * NB + b;
  const int q0 = qb * 128;
  const unsigned short* ktp = kt + (size_t)bh * NT * ND;
  const unsigned short* qtp = qt + ((size_t)bh * NT + q0) * ND;
  const unsigned short* vp  = vbuf + (size_t)bh * ND * NT;
  const int l15 = lane & 15, g = lane >> 4;

  if (tid < 128) colacc[tid] = 0.f;
  stage_k512(qtp, lds, QOFF, tid);
  stage_k512(ktp, lds, KOFF0, tid);
  stage_v512(vp, 0, lds, VOFF0, tid);
#pragma unroll
  for (int j = 0; j < 2; ++j) {
    unsigned long long bb = __ballot(mask[b * NT + wid * 128 + j * 64 + lane] != 0);
    if (lane == 0) mbits[wid * 2 + j] = bb;
  }
  i32x4 qm4[2];
#pragma unroll
  for (int nf = 0; nf < 2; ++nf)
    qm4[nf] = *(const i32x4*)(mask + b * NT + q0 + wc * 32 + nf * 16 + g * 4);
  asm volatile("s_waitcnt vmcnt(0)" ::: "memory");
  __syncthreads();

  s16x8 qf[2][2];
#pragma unroll
  for (int nf = 0; nf < 2; ++nf)
#pragma unroll
    for (int ks = 0; ks < 2; ++ks)
      qf[nf][ks] = frag_ld(lds, QOFF, wc * 32 + nf * 16 + l15, ks, lane);

  unsigned int kmask32 = 0;
#pragma unroll
  for (int t = 0; t < 8; ++t) {
    const unsigned long long w64 = mbits[t * 2 + wr];
#pragma unroll
    for (int mf = 0; mf < 4; ++mf)
      kmask32 |= (unsigned int)((w64 >> (mf * 16 + l15)) & 1ull) << (t * 4 + mf);
  }

  const float scl = 0.125f * 1.44269504f;
  u16x4 preg[8][8];            // unnormalized bf16 P, all indices compile-time
  f32x4 cs4[2] = {(f32x4){0.f,0.f,0.f,0.f}, (f32x4){0.f,0.f,0.f,0.f}};
  f32x4 cacc[4];
#pragma unroll
  for (int i = 0; i < 4; ++i) cacc[i] = (f32x4){0.f, 0.f, 0.f, 0.f};

  // ---- Phase A ----
#pragma unroll
  for (int t = 0; t < 8; ++t) {
    if (t > 0) __builtin_amdgcn_s_barrier();   // readers of target bufs done
    if (t < 7) {
      stage_k512(ktp + (size_t)(t + 1) * 128 * ND, lds, (t & 1) ? KOFF0 : KOFF1, tid);
      stage_v512(vp, (t + 1) * 128, lds, (t & 1) ? VOFF0 : VOFF1, tid);
      asm volatile("s_waitcnt vmcnt(4)" ::: "memory");   // K(t),V(t) resident
    } else {
      asm volatile("s_waitcnt vmcnt(0)" ::: "memory");
    }
    __builtin_amdgcn_s_barrier();
    const int koff = (t & 1) ? KOFF1 : KOFF0;
    const int voff = (t & 1) ? VOFF1 : VOFF0;

    // QK(t)
    f32x4 sacc[4][2];
#pragma unroll
    for (int i = 0; i < 4; ++i)
#pragma unroll
      for (int j = 0; j < 2; ++j) sacc[i][j] = (f32x4){0.f, 0.f, 0.f, 0.f};
#pragma unroll
    for (int ks = 0; ks < 2; ++ks) {
      s16x8 kf[4];
#pragma unroll
      for (int mf = 0; mf < 4; ++mf)
        kf[mf] = frag_ld(lds, koff, wr * 64 + mf * 16 + l15, ks, lane);
#pragma unroll
      for (int mf = 0; mf < 4; ++mf)
#pragma unroll
        for (int nf = 0; nf < 2; ++nf)
          sacc[mf][nf] = __builtin_amdgcn_mfma_f32_16x16x32_bf16(qf[nf][ks], kf[mf], sacc[mf][nf], 0, 0, 0);
    }

    // exp once; pack bf16 P to regs; colsum accum; relay raw P -> LDS
#pragma unroll
    for (int mf = 0; mf < 4; ++mf) {
      const float kz = ((kmask32 >> (t * 4 + mf)) & 1u) ? 0.f : 1.f;
      const int kloc = wr * 64 + mf * 16 + l15;
#pragma unroll
      for (int nf = 0; nf < 2; ++nf) {
        f32x4 p;
#pragma unroll
        for (int i = 0; i < 4; ++i) {
          p[i] = kz * fexp2(sacc[mf][nf][i] * scl);
          cs4[nf][i] += p[i];
        }
        u16x4 pr;
#pragma unroll
        for (int i = 0; i < 4; ++i) pr[i] = cvt_bf16(p[i]);
        preg[t][mf * 2 + nf] = pr;
        const int qrow = wc * 32 + nf * 16 + g * 4;
#pragma unroll
        for (int i = 0; i < 4; ++i) {
          const int row = qrow + i;
          *(unsigned short*)(lds + POFF + row * 256 + (((kloc >> 3) ^ (row & 15)) << 4)
                             + ((kloc & 7) << 1)) = pr[i];
        }
      }
    }
    asm volatile("s_waitcnt lgkmcnt(0)" ::: "memory");
    __builtin_amdgcn_sched_barrier(0);
    __builtin_amdgcn_s_barrier();

    // PV(t): ctx_unnorm[d][q] += V[d][k] * P[k][q]
#pragma unroll
    for (int ks2 = 0; ks2 < 4; ++ks2) {
      const int chunk = (ks2 << 2) + g;
      s16x8 vf[4];
#pragma unroll
      for (int mf = 0; mf < 4; ++mf) {
        const int d = mf * 16 + l15;
        vf[mf] = *(const s16x8*)(lds + voff + d * 256 + ((chunk ^ (d & 15)) << 4));
      }
      const int qloc = wid * 16 + l15;
      s16x8 pf = *(const s16x8*)(lds + POFF + qloc * 256 + ((chunk ^ (qloc & 15)) << 4));
#pragma unroll
      for (int mf = 0; mf < 4; ++mf)
        cacc[mf] = __builtin_amdgcn_mfma_f32_16x16x32_bf16(vf[mf], pf, cacc[mf], 0, 0, 0);
    }
  }

  // ---- Phase B: colsum reduce + sq; ctx epilogue ----
#pragma unroll
  for (int nf = 0; nf < 2; ++nf)
#pragma unroll
    for (int i = 0; i < 4; ++i) {
      float v = cs4[nf][i];
      v += __shfl_xor(v, 1); v += __shfl_xor(v, 2);
      v += __shfl_xor(v, 4); v += __shfl_xor(v, 8);
      cs4[nf][i] = v;
    }
  if (l15 == 0) {
#pragma unroll
    for (int nf = 0; nf < 2; ++nf)
#pragma unroll
      for (int i = 0; i < 4; ++i)
        atomicAdd(&colacc[wc * 32 + nf * 16 + g * 4 + i], cs4[nf][i]);
  }
  __syncthreads();
  f32x4 sq4[2];
#pragma unroll
  for (int nf = 0; nf < 2; ++nf)
#pragma unroll
    for (int i = 0; i < 4; ++i)
      sq4[nf][i] = qm4[nf][i] ? 0.f : 1.0f / colacc[wc * 32 + nf * 16 + g * 4 + i];

  {
    const int qe = wid * 16 + l15;
    const float sqe = mask[b * NT + q0 + qe] ? 0.f : 1.0f / colacc[qe];
#pragma unroll
    for (int mf = 0; mf < 4; ++mf) {
      u16x4 v4;
#pragma unroll
      for (int i = 0; i < 4; ++i) v4[i] = cvt_bf16(cacc[mf][i] * sqe);
      *(u16x4*)(ctxT + ((size_t)b * NT + q0 + qe) * NC + h * ND + mf * 16 + g * 4) = v4;
    }
  }

  // ---- Phase C: pure att store sweep (no sync) ----
  float* attb = att + (size_t)hb * NT * NT + q0 + wc * 32 + g * 4;
#pragma unroll
  for (int t = 0; t < 8; ++t) {
#pragma unroll
    for (int mf = 0; mf < 4; ++mf) {
      const int kg = t * 128 + wr * 64 + mf * 16 + l15;
#pragma unroll
      for (int nf = 0; nf < 2; ++nf) {
        const u16x4 pr = preg[t][mf * 2 + nf];
        f32x4 p4;
#pragma unroll
        for (int i = 0; i < 4; ++i) p4[i] = bf16_to_f32(pr[i]) * sq4[nf][i];
        __builtin_nontemporal_store(p4, (f32x4*)(attb + (size_t)kg * NT + nf * 16));
      }
    }
  }
}

// ---------------- out-projection + residual + GN partial sums (128², full chip) ----------------
__global__ __launch_bounds__(256) void k_outgemm(const unsigned short* __restrict__ Wo,
                                                 const unsigned short* __restrict__ ctxT,
                                                 const float* __restrict__ x,
                                                 float* __restrict__ y0,
                                                 float* __restrict__ partials) {
  __shared__ char lds[32832];
  const int tid = threadIdx.x, lane = tid & 63, wave = tid >> 6;
  const int wr = wave >> 1, wc = wave & 1;
  const int bm = blockIdx.x, bn = blockIdx.y, b = blockIdx.z;
  const unsigned short* A = Wo + (size_t)bm * 128 * NC;
  const unsigned short* Bt = ctxT + ((size_t)b * NT + (size_t)bn * 128) * NC;
  f32x4 acc[4][4];
  gemm_core_128<NC>(A, Bt, NC, NC, lds, tid, acc);

  float lsum = 0.f, lsq = 0.f;
#pragma unroll
  for (int mf = 0; mf < 4; ++mf) {
#pragma unroll
    for (int nf = 0; nf < 4; ++nf) {
      const int gc = bn * 128 + wc * 64 + nf * 16 + (lane & 15);
#pragma unroll
      for (int i = 0; i < 4; ++i) {
        const int gr = bm * 128 + wr * 64 + mf * 16 + ((lane >> 4) << 2) + i;
        const size_t idx = ((size_t)b * NC + gr) * NT + gc;
        const float v = acc[mf][nf][i] + x[idx];
        y0[idx] = v;
        lsum += v; lsq += v * v;
      }
    }
  }
#pragma unroll
  for (int off = 32; off; off >>= 1) {
    lsum += __shfl_xor(lsum, off);
    lsq += __shfl_xor(lsq, off);
  }
  __syncthreads();
  float* red = (float*)(lds + 32768);
  if (lane == 0) { red[wave * 2] = lsum; red[wave * 2 + 1] = lsq; }
  __syncthreads();
  if (tid == 0) {
    const float s = red[0] + red[2] + red[4] + red[6];
    const float qq = red[1] + red[3] + red[5] + red[7];
    const int bi = bm * 8 + bn;
    partials[((size_t)b * 64 + bi) * 2] = s;
    partials[((size_t)b * 64 + bi) * 2 + 1] = qq;
  }
}

__global__ void k_gnstats(const float* __restrict__ partials, float* __restrict__ gnp) {
  const int b = blockIdx.x, t = threadIdx.x;
  float s = partials[((size_t)b * 64 + t) * 2];
  float q = partials[((size_t)b * 64 + t) * 2 + 1];
#pragma unroll
  for (int off = 32; off; off >>= 1) {
    s += __shfl_xor(s, off);
    q += __shfl_xor(q, off);
  }
  if (t == 0) {
    const float n = 1048576.f;
    const float mean = s / n;
    const float var = q / n - mean * mean;
    gnp[b * 2] = mean;
    gnp[b * 2 + 1] = rsqrtf(var + 1e-5f);
  }
}

__global__ __launch_bounds__(256) void k_gnapply(const float* __restrict__ y0,
                                                 const float* __restrict__ gnp,
                                                 const float* __restrict__ gw,
                                                 const float* __restrict__ gb,
                                                 float* __restrict__ out) {
  const size_t n4 = (size_t)NB * NC * NT / 4;
  const size_t stride = (size_t)gridDim.x * blockDim.x;
  for (size_t i = (size_t)blockIdx.x * blockDim.x + threadIdx.x; i < n4; i += stride) {
    const size_t base = i * 4;
    const int b = (int)(base >> 20);
    const int c = (int)((base >> 10) & 1023);
    const f32x4 v = *(const f32x4*)(y0 + base);
    const float m = gnp[b * 2], r = gnp[b * 2 + 1];
    const float sw = gw[c] * r, sb = gb[c];
    f32x4 o;
#pragma unroll
    for (int j = 0; j < 4; ++j) o[j] = (v[j] - m) * sw + sb;
    *(f32x4*)(out + base) = o;
  }
}

extern "C" void kernel_launch(void* const* d_in, const int* in_sizes, int n_in,
                              void* d_out, int out_size, void* d_ws, size_t ws_size,
                              hipStream_t stream) {
  (void)in_sizes; (void)n_in; (void)out_size; (void)ws_size;
  const float* x     = (const float*)d_in[0];
  const int*   mask  = (const int*)d_in[1];
  const float* w_kvq = (const float*)d_in[2];
  const float* w_out = (const float*)d_in[3];
  const float* gnw   = (const float*)d_in[4];
  const float* gnb   = (const float*)d_in[5];
  float* outy = (float*)d_out;
  float* att  = outy + (size_t)NB * NC * NT;  // att_ret region of d_out

  char* ws = (char*)d_ws;
  unsigned short* wkvq_bf = (unsigned short*)(ws);             //  6,291,456 B
  unsigned short* wout_bf = (unsigned short*)(ws + 6291456);   //  2,097,152 B
  unsigned short* xT      = (unsigned short*)(ws + 8388608);   // 16,777,216 B
  unsigned short* ctxT    = xT;                                // alias: xT dead after gemm1
  unsigned short* kt      = (unsigned short*)(ws + 25165824);  // 16,777,216 B
  unsigned short* qt      = (unsigned short*)(ws + 41943040);  // 16,777,216 B
  float*          y0      = (float*)(ws + 25165824);           // alias kt+qt: dead after att
  unsigned short* vbuf    = (unsigned short*)(ws + 58720256);  // 16,777,216 B
  float*          part    = (float*)(ws + 76021760);           //      4,096 B
  float*          gnp     = (float*)(ws + 76025856);           //         64 B

  k_prep<<<2048, 256, 0, stream>>>(w_kvq, wkvq_bf, w_out, wout_bf);
  k_xT<<<dim3(32, 32, 8), dim3(32, 8), 0, stream>>>(x, xT);
  k_gemm1_256<<<384, 512, 0, stream>>>(wkvq_bf, xT, kt, qt, vbuf);
  k_att2<<<dim3(128, 8), 512, 0, stream>>>(kt, qt, vbuf, mask, att, ctxT);
  k_outgemm<<<dim3(8, 8, 8), 256, 0, stream>>>(wout_bf, ctxT, x, y0, part);
  k_gnstats<<<8, 64, 0, stream>>>(part, gnp);
  k_gnapply<<<4096, 256, 0, stream>>>(y0, gnp, gnw, gnb, outy);
}

// Round 10
// 377.961 us; speedup vs baseline: 1.5414x; 1.0970x over previous
//
#include <hip/hip_runtime.h>

#define DEVI __device__ __forceinline__

typedef __attribute__((ext_vector_type(8))) short s16x8;
typedef __attribute__((ext_vector_type(4))) float f32x4;
typedef __attribute__((ext_vector_type(4))) unsigned short u16x4;
typedef __attribute__((ext_vector_type(4))) int i32x4;

static constexpr int NB = 8;      // batch
static constexpr int NC = 1024;   // channels
static constexpr int NT = 1024;   // time
static constexpr int NH = 16;     // heads
static constexpr int ND = 64;     // head dim

DEVI unsigned short cvt_bf16(float f) {
  unsigned int u = __builtin_bit_cast(unsigned int, f);
  u += 0x7fffu + ((u >> 16) & 1u);
  return (unsigned short)(u >> 16);
}

DEVI float bf16_to_f32(unsigned short s) {
  unsigned int u = (unsigned int)s << 16;
  return __builtin_bit_cast(float, u);
}

DEVI float fexp2(float x) {
#if __has_builtin(__builtin_amdgcn_exp2f)
  return __builtin_amdgcn_exp2f(x);
#else
  return exp2f(x);
#endif
}

// ---- 256-thread stager (used by gemm_core_128) ----
template<int ROWS>
DEVI void stage_tile(const unsigned short* g, int ld, char* lds, int loff, int tid) {
  const int wave = tid >> 6;
  const int lane = tid & 63;
#pragma unroll
  for (int r = 0; r < (ROWS >> 5); ++r) {
    const int row = r * 32 + wave * 8 + (lane >> 3);
    const int c  = lane & 7;
    const int cg = c ^ (row & 7);
    const char* src = (const char*)g + (size_t)row * ld * 2 + cg * 16;
    char* dst = lds + loff + (r * 32 + wave * 8) * 128;  // wave-uniform
    __builtin_amdgcn_global_load_lds((const __attribute__((address_space(1))) void*)src,
                                     (__attribute__((address_space(3))) void*)dst,
                                     16, 0, 0);
  }
}

// ---- 512-thread stagers ----
// Q: 64 rows x 64 bf16 (128B/row), 1 VMEM op/thread.
DEVI void stage_q512(const unsigned short* g, char* lds, int loff, int tid) {
  const int wave = tid >> 6, lane = tid & 63;
  const int row = wave * 8 + (lane >> 3);
  const int c = lane & 7, cg = c ^ (row & 7);
  const char* src = (const char*)g + (size_t)row * 128 + cg * 16;
  char* dst = lds + loff + wave * 1024;
  __builtin_amdgcn_global_load_lds((const __attribute__((address_space(1))) void*)src,
                                   (__attribute__((address_space(3))) void*)dst,
                                   16, 0, 0);
}
// K: 128 rows x 64 bf16 (128B/row), 2 VMEM ops/thread.
DEVI void stage_k512(const unsigned short* g, char* lds, int loff, int tid) {
  const int wave = tid >> 6, lane = tid & 63;
#pragma unroll
  for (int r = 0; r < 2; ++r) {
    const int row = r * 64 + wave * 8 + (lane >> 3);
    const int c = lane & 7, cg = c ^ (row & 7);
    const char* src = (const char*)g + (size_t)row * 128 + cg * 16;
    char* dst = lds + loff + (r * 64 + wave * 8) * 128;
    __builtin_amdgcn_global_load_lds((const __attribute__((address_space(1))) void*)src,
                                     (__attribute__((address_space(3))) void*)dst,
                                     16, 0, 0);
  }
}
// V: 64 rows (d) x 128 bf16 (256B/row), 2 VMEM ops/thread.
DEVI void stage_v512(const unsigned short* v, int k0, char* lds, int loff, int tid) {
  const int wave = tid >> 6, lane = tid & 63;
#pragma unroll
  for (int r = 0; r < 2; ++r) {
    const int d = r * 32 + wave * 4 + (lane >> 4);
    const int c = lane & 15, cg = c ^ (d & 15);
    const char* src = (const char*)(v + (size_t)d * NT + k0 + cg * 8);
    char* dst = lds + loff + (r * 32 + wave * 4) * 256;
    __builtin_amdgcn_global_load_lds((const __attribute__((address_space(1))) void*)src,
                                     (__attribute__((address_space(3))) void*)dst,
                                     16, 0, 0);
  }
}

// Fragment read for mfma_f32_16x16x32_bf16: lane holds A[row][ks*32+(lane>>4)*8 .. +8]
DEVI s16x8 frag_ld(const char* lds, int loff, int row, int ks, int lane) {
  const int chunk = (ks * 4 + (lane >> 4)) ^ (row & 7);
  return *(const s16x8*)(lds + loff + row * 128 + chunk * 16);
}

// 128x128 tile TN GEMM core (256 threads)
template<int KTOT>
DEVI void gemm_core_128(const unsigned short* A, const unsigned short* Bt,
                        int ldA, int ldB, char* lds, int tid, f32x4 acc[4][4]) {
  const int lane = tid & 63;
  const int wave = tid >> 6;
  const int wr = wave >> 1, wc = wave & 1;
#pragma unroll
  for (int i = 0; i < 4; ++i)
#pragma unroll
    for (int j = 0; j < 4; ++j)
      acc[i][j] = (f32x4){0.f, 0.f, 0.f, 0.f};
  for (int k0 = 0; k0 < KTOT; k0 += 64) {
    __syncthreads();
    stage_tile<128>(A + k0, ldA, lds, 0, tid);
    stage_tile<128>(Bt + k0, ldB, lds, 16384, tid);
    asm volatile("s_waitcnt vmcnt(0)" ::: "memory");
    __syncthreads();
#pragma unroll
    for (int ks = 0; ks < 2; ++ks) {
      s16x8 af[4], bfr[4];
#pragma unroll
      for (int mf = 0; mf < 4; ++mf)
        af[mf] = frag_ld(lds, 0, wr * 64 + mf * 16 + (lane & 15), ks, lane);
#pragma unroll
      for (int nf = 0; nf < 4; ++nf)
        bfr[nf] = frag_ld(lds, 16384, wc * 64 + nf * 16 + (lane & 15), ks, lane);
#pragma unroll
      for (int mf = 0; mf < 4; ++mf)
#pragma unroll
        for (int nf = 0; nf < 4; ++nf)
          acc[mf][nf] = __builtin_amdgcn_mfma_f32_16x16x32_bf16(af[mf], bfr[nf], acc[mf][nf], 0, 0, 0);
    }
  }
}

// ---------------- prep ----------------
__global__ __launch_bounds__(256) void k_prep(const float* __restrict__ wkvq,
                                              unsigned short* __restrict__ wkvq_bf,
                                              const float* __restrict__ wout,
                                              unsigned short* __restrict__ wout_bf) {
  const int n1 = 3 * NC * NC / 4, n2 = NC * NC / 4;
  const int stride = gridDim.x * blockDim.x;
  for (int i = blockIdx.x * blockDim.x + threadIdx.x; i < n1 + n2; i += stride) {
    const float* src = (i < n1) ? wkvq + (size_t)i * 4 : wout + (size_t)(i - n1) * 4;
    unsigned short* dst = (i < n1) ? wkvq_bf + (size_t)i * 4 : wout_bf + (size_t)(i - n1) * 4;
    f32x4 v = *(const f32x4*)src;
    u16x4 o;
#pragma unroll
    for (int j = 0; j < 4; ++j) o[j] = cvt_bf16(v[j]);
    *(u16x4*)dst = o;
  }
}

// x [B,C,T] f32 -> xT [B,T,C] bf16
__global__ void k_xT(const float* __restrict__ x, unsigned short* __restrict__ xT) {
  __shared__ float tl[32][33];
  const int bz = blockIdx.z;
  const int t0 = blockIdx.x * 32, c0 = blockIdx.y * 32;
  const int tx = threadIdx.x, ty = threadIdx.y;  // (32,8)
#pragma unroll
  for (int j = 0; j < 4; ++j)
    tl[ty + j * 8][tx] = x[((size_t)bz * NC + c0 + ty + j * 8) * NT + t0 + tx];
  __syncthreads();
#pragma unroll
  for (int j = 0; j < 4; ++j)
    xT[((size_t)bz * NT + t0 + ty + j * 8) * NC + c0 + tx] = cvt_bf16(tl[tx][ty + j * 8]);
}

// ---------------- QKV projection: 256x256 tile, BK=32, 4-slot ring, counted vmcnt ----------------
__global__ __launch_bounds__(512, 2) void k_gemm1_256(const unsigned short* __restrict__ W,
                                                      const unsigned short* __restrict__ xT,
                                                      unsigned short* __restrict__ kt,
                                                      unsigned short* __restrict__ qt,
                                                      unsigned short* __restrict__ vbuf) {
  __shared__ char lds[131072];
  const int tid = threadIdx.x, lane = tid & 63, wid = tid >> 6;
  const int wr = wid >> 2, wc = wid & 3;
  const int gid = blockIdx.x;
  const int wg = (gid & 7) * 48 + (gid >> 3);
  const int bn = wg / 12, bm = wg % 12;

  const int r = tid >> 2, ccc = tid & 3;
  const int cg = ccc ^ ((r ^ (r >> 2)) & 3);
  const unsigned short* srcA = W + (size_t)(bm * 256 + r) * NC + cg * 8;
  const unsigned short* srcB = xT + (size_t)(bn * 256 + r) * NC + cg * 8;

  auto stageA = [&](int t) {
    char* d = lds + (t & 3) * 32768 + wid * 1024;
    const unsigned short* s = srcA + t * 32;
    __builtin_amdgcn_global_load_lds((const __attribute__((address_space(1))) void*)s,
                                     (__attribute__((address_space(3))) void*)d, 16, 0, 0);
    __builtin_amdgcn_global_load_lds((const __attribute__((address_space(1))) void*)(s + 128 * NC),
                                     (__attribute__((address_space(3))) void*)(d + 8192), 16, 0, 0);
  };
  auto stageB = [&](int t) {
    char* d = lds + (t & 3) * 32768 + 16384 + wid * 1024;
    const unsigned short* s = srcB + t * 32;
    __builtin_amdgcn_global_load_lds((const __attribute__((address_space(1))) void*)s,
                                     (__attribute__((address_space(3))) void*)d, 16, 0, 0);
    __builtin_amdgcn_global_load_lds((const __attribute__((address_space(1))) void*)(s + 128 * NC),
                                     (__attribute__((address_space(3))) void*)(d + 8192), 16, 0, 0);
  };

  const int l15 = lane & 15, lg = lane >> 4;
  const int rA = wr * 128 + l15;
  const int offA = rA * 64 + (((lg ^ (rA ^ (rA >> 2))) & 3) << 4) + ((lg & ~3) << 4);
  const int rB = wc * 64 + l15;
  const int offB = 16384 + rB * 64 + (((lg ^ (rB ^ (rB >> 2))) & 3) << 4) + ((lg & ~3) << 4);

  f32x4 acc[8][4];
#pragma unroll
  for (int i = 0; i < 8; ++i)
#pragma unroll
    for (int j = 0; j < 4; ++j) acc[i][j] = (f32x4){0.f, 0.f, 0.f, 0.f};

  stageA(0); stageB(0); stageA(1); stageB(1); stageA(2); stageB(2);
  asm volatile("s_waitcnt vmcnt(8)" ::: "memory");
  __builtin_amdgcn_s_barrier();

#pragma unroll
  for (int t = 0; t < 32; ++t) {
    const int slot = (t & 3) * 32768;
    s16x8 af[8], bf[4];
#pragma unroll
    for (int nf = 0; nf < 4; ++nf) bf[nf] = *(const s16x8*)(lds + slot + offB + nf * 1024);
#pragma unroll
    for (int mf = 0; mf < 4; ++mf) af[mf] = *(const s16x8*)(lds + slot + offA + mf * 1024);
    if (t < 29) stageA(t + 3);
    __builtin_amdgcn_s_barrier();
    asm volatile("s_waitcnt lgkmcnt(0)" ::: "memory");
    __builtin_amdgcn_sched_barrier(0);
    __builtin_amdgcn_s_setprio(1);
#pragma unroll
    for (int mf = 0; mf < 4; ++mf)
#pragma unroll
      for (int nf = 0; nf < 4; ++nf)
        acc[mf][nf] = __builtin_amdgcn_mfma_f32_16x16x32_bf16(af[mf], bf[nf], acc[mf][nf], 0, 0, 0);
    __builtin_amdgcn_s_setprio(0);
    __builtin_amdgcn_s_barrier();
#pragma unroll
    for (int mf = 4; mf < 8; ++mf) af[mf] = *(const s16x8*)(lds + slot + offA + mf * 1024);
    if (t < 29) stageB(t + 3);
    if (t < 29)       asm volatile("s_waitcnt vmcnt(8)" ::: "memory");
    else if (t == 29) asm volatile("s_waitcnt vmcnt(4)" ::: "memory");
    else              asm volatile("s_waitcnt vmcnt(0)" ::: "memory");
    __builtin_amdgcn_s_barrier();
    asm volatile("s_waitcnt lgkmcnt(0)" ::: "memory");
    __builtin_amdgcn_sched_barrier(0);
    __builtin_amdgcn_s_setprio(1);
#pragma unroll
    for (int mf = 4; mf < 8; ++mf)
#pragma unroll
      for (int nf = 0; nf < 4; ++nf)
        acc[mf][nf] = __builtin_amdgcn_mfma_f32_16x16x32_bf16(af[mf], bf[nf], acc[mf][nf], 0, 0, 0);
    __builtin_amdgcn_s_setprio(0);
    __builtin_amdgcn_s_barrier();
  }

  const int part = bm >> 2;
  const int d0base = lg << 2;
#pragma unroll
  for (int mf = 0; mf < 8; ++mf) {
    const int h = ((bm & 3) << 2) + (wr << 1) + (mf >> 2);
    const int d0 = ((mf & 3) << 4) + d0base;
#pragma unroll
    for (int nf = 0; nf < 4; ++nf) {
      const int tg = bn * 256 + wc * 64 + nf * 16 + l15;
      const int b = tg >> 10, tt = tg & 1023;
      u16x4 v4;
#pragma unroll
      for (int i = 0; i < 4; ++i) v4[i] = cvt_bf16(acc[mf][nf][i]);
      if (part == 0) {
        *(u16x4*)(kt + (((size_t)(b * NH + h) * NT + tt) * ND + d0)) = v4;
      } else if (part == 1) {
        const size_t basev = ((size_t)(b * NH + h) * ND + d0) * NT + tt;
        vbuf[basev] = v4[0]; vbuf[basev + NT] = v4[1];
        vbuf[basev + 2 * NT] = v4[2]; vbuf[basev + 3 * NT] = v4[3];
      } else {
        *(u16x4*)(qt + (((size_t)(b * NH + h) * NT + tt) * ND + d0)) = v4;
      }
    }
  }
}

// ---------------- attention: single QK pass, q-tile 64 (preg = 64 VGPR) ----------------
// 512 threads, 8 waves: wr=wid&1 (k-half for QK, d-half for PV), wq=wid>>1 (q-quarter 16).
// Phase A per k-tile (K dbuf, V single, counted vmcnt, NO global stores in loop):
//   QK once -> exp once -> pack bf16 P to preg + colsum accum + relay P via LDS -> PV unnorm.
// Phase B: colsum reduce -> sq; ctx epilogue * sq.
// Phase C: pure att store sweep (preg * sq), no syncs.
__global__ __launch_bounds__(512, 2) void k_att3(const unsigned short* __restrict__ kt,
                                                 const unsigned short* __restrict__ qt,
                                                 const unsigned short* __restrict__ vbuf,
                                                 const int* __restrict__ mask,
                                                 float* __restrict__ att,
                                                 unsigned short* __restrict__ ctxT) {
  __shared__ char lds[74240];
  constexpr int QOFF = 0, KOFF0 = 8192, KOFF1 = 24576, VOFF = 40960, POFF = 57344;
  constexpr int COFF = 73728;
  float* colacc = (float*)(lds + COFF);                                 // 64 f32
  unsigned long long* mbits = (unsigned long long*)(lds + COFF + 256);  // 16 u64
  const int tid = threadIdx.x, lane = tid & 63, wid = tid >> 6;
  const int wr = wid & 1, wq = wid >> 1;
  const int bh = blockIdx.x, qb = blockIdx.y;   // x=bh so q-replicas share an XCD
  const int b = bh >> 4, h = bh & 15, hb = h * NB + b;
  const int q0 = qb * 64;
  const unsigned short* ktp = kt + (size_t)bh * NT * ND;
  const unsigned short* qtp = qt + ((size_t)bh * NT + q0) * ND;
  const unsigned short* vp  = vbuf + (size_t)bh * ND * NT;
  const int l15 = lane & 15, g = lane >> 4;

  if (tid < 64) colacc[tid] = 0.f;
  stage_q512(qtp, lds, QOFF, tid);
  stage_k512(ktp, lds, KOFF0, tid);
  stage_v512(vp, 0, lds, VOFF, tid);
#pragma unroll
  for (int j = 0; j < 2; ++j) {
    unsigned long long bb = __ballot(mask[b * NT + wid * 128 + j * 64 + lane] != 0);
    if (lane == 0) mbits[wid * 2 + j] = bb;
  }
  const i32x4 qm4 = *(const i32x4*)(mask + b * NT + q0 + wq * 16 + g * 4);
  asm volatile("s_waitcnt vmcnt(0)" ::: "memory");
  __syncthreads();   // Q/K0/V0 + mbits resident; vmcnt exactly 0

  s16x8 qf[2];
#pragma unroll
  for (int ks = 0; ks < 2; ++ks)
    qf[ks] = frag_ld(lds, QOFF, wq * 16 + l15, ks, lane);

  // per-thread k-mask: bit (t*4+mf) for k = t*128 + wr*64 + mf*16 + l15
  unsigned int kmask32 = 0;
#pragma unroll
  for (int t = 0; t < 8; ++t) {
    const unsigned long long w64 = mbits[t * 2 + wr];
#pragma unroll
    for (int mf = 0; mf < 4; ++mf)
      kmask32 |= (unsigned int)((w64 >> (mf * 16 + l15)) & 1ull) << (t * 4 + mf);
  }

  const float scl = 0.125f * 1.44269504f;
  u16x4 preg[8][4];            // unnormalized bf16 P, all indices compile-time
  f32x4 cs4 = (f32x4){0.f, 0.f, 0.f, 0.f};
  f32x4 cacc[2];
  cacc[0] = (f32x4){0.f, 0.f, 0.f, 0.f};
  cacc[1] = (f32x4){0.f, 0.f, 0.f, 0.f};

  // ---- Phase A ----
#pragma unroll
  for (int t = 0; t < 8; ++t) {
    const int koff = (t & 1) ? KOFF1 : KOFF0;
    // QK(t): K(t), V(t) resident at loop top
    f32x4 sacc[4];
#pragma unroll
    for (int i = 0; i < 4; ++i) sacc[i] = (f32x4){0.f, 0.f, 0.f, 0.f};
#pragma unroll
    for (int ks = 0; ks < 2; ++ks) {
      s16x8 kf[4];
#pragma unroll
      for (int mf = 0; mf < 4; ++mf)
        kf[mf] = frag_ld(lds, koff, wr * 64 + mf * 16 + l15, ks, lane);
#pragma unroll
      for (int mf = 0; mf < 4; ++mf)
        sacc[mf] = __builtin_amdgcn_mfma_f32_16x16x32_bf16(qf[ks], kf[mf], sacc[mf], 0, 0, 0);
    }
    __builtin_amdgcn_s_barrier();          // all waves done reading K[t&1]... (K[(t+1)&1] free)
    if (t < 7) stage_k512(ktp + (size_t)(t + 1) * 128 * ND, lds, (t & 1) ? KOFF0 : KOFF1, tid);

    // exp once; pack bf16 P; colsum; relay raw P -> LDS (P region free: PV(t-1) done)
#pragma unroll
    for (int mf = 0; mf < 4; ++mf) {
      const float kz = ((kmask32 >> (t * 4 + mf)) & 1u) ? 0.f : 1.f;
      const int kloc = wr * 64 + mf * 16 + l15;
      f32x4 p;
#pragma unroll
      for (int i = 0; i < 4; ++i) {
        p[i] = kz * fexp2(sacc[mf][i] * scl);
        cs4[i] += p[i];
      }
      u16x4 pr;
#pragma unroll
      for (int i = 0; i < 4; ++i) pr[i] = cvt_bf16(p[i]);
      preg[t][mf] = pr;
      const int qrow = wq * 16 + g * 4;
#pragma unroll
      for (int i = 0; i < 4; ++i) {
        const int row = qrow + i;
        *(unsigned short*)(lds + POFF + row * 256 + (((kloc >> 3) ^ (row & 15)) << 4)
                           + ((kloc & 7) << 1)) = pr[i];
      }
    }
    asm volatile("s_waitcnt lgkmcnt(0)" ::: "memory");
    __builtin_amdgcn_sched_barrier(0);
    __builtin_amdgcn_s_barrier();          // P complete
    if (t < 7) asm volatile("s_waitcnt vmcnt(2)" ::: "memory");  // V(t) resident (retires all but K(t+1))
    else       asm volatile("s_waitcnt vmcnt(0)" ::: "memory");

    // PV(t): ctx_unnorm[d][q] += V[d][k] * P[k][q]; wave: d-half wr, q-quarter wq
#pragma unroll
    for (int ks2 = 0; ks2 < 4; ++ks2) {
      const int chunk = (ks2 << 2) + g;
      s16x8 vf[2];
#pragma unroll
      for (int mf2 = 0; mf2 < 2; ++mf2) {
        const int d = wr * 32 + mf2 * 16 + l15;
        vf[mf2] = *(const s16x8*)(lds + VOFF + d * 256 + ((chunk ^ (d & 15)) << 4));
      }
      const int qloc = wq * 16 + l15;
      s16x8 pf = *(const s16x8*)(lds + POFF + qloc * 256 + ((chunk ^ (qloc & 15)) << 4));
#pragma unroll
      for (int mf2 = 0; mf2 < 2; ++mf2)
        cacc[mf2] = __builtin_amdgcn_mfma_f32_16x16x32_bf16(vf[mf2], pf, cacc[mf2], 0, 0, 0);
    }
    __builtin_amdgcn_s_barrier();          // V free
    if (t < 7) {
      stage_v512(vp, (t + 1) * 128, lds, VOFF, tid);
      asm volatile("s_waitcnt vmcnt(2)" ::: "memory");  // K(t+1) resident (V(t+1) still in flight)
      __builtin_amdgcn_s_barrier();
    }
  }

  // ---- Phase B: colsum reduce + sq; ctx epilogue ----
#pragma unroll
  for (int i = 0; i < 4; ++i) {
    float v = cs4[i];
    v += __shfl_xor(v, 1); v += __shfl_xor(v, 2);
    v += __shfl_xor(v, 4); v += __shfl_xor(v, 8);
    cs4[i] = v;
  }
  if (l15 == 0) {
#pragma unroll
    for (int i = 0; i < 4; ++i)
      atomicAdd(&colacc[wq * 16 + g * 4 + i], cs4[i]);
  }
  __syncthreads();
  f32x4 sq4;
#pragma unroll
  for (int i = 0; i < 4; ++i)
    sq4[i] = qm4[i] ? 0.f : 1.0f / colacc[wq * 16 + g * 4 + i];

  {  // ctx epilogue: D[d][q], col=q=l15, row=d = wr*32 + mf2*16 + g*4+i
    const int qe = wq * 16 + l15;
    const float sqe = mask[b * NT + q0 + qe] ? 0.f : 1.0f / colacc[qe];
#pragma unroll
    for (int mf2 = 0; mf2 < 2; ++mf2) {
      u16x4 v4;
#pragma unroll
      for (int i = 0; i < 4; ++i) v4[i] = cvt_bf16(cacc[mf2][i] * sqe);
      *(u16x4*)(ctxT + ((size_t)b * NT + q0 + qe) * NC + h * ND + wr * 32 + mf2 * 16 + g * 4) = v4;
    }
  }

  // ---- Phase C: pure att store sweep (no sync) ----
  float* attb = att + (size_t)hb * NT * NT + q0 + wq * 16 + g * 4;
#pragma unroll
  for (int t = 0; t < 8; ++t) {
#pragma unroll
    for (int mf = 0; mf < 4; ++mf) {
      const int kg = t * 128 + wr * 64 + mf * 16 + l15;
      const u16x4 pr = preg[t][mf];
      f32x4 p4;
#pragma unroll
      for (int i = 0; i < 4; ++i) p4[i] = bf16_to_f32(pr[i]) * sq4[i];
      __builtin_nontemporal_store(p4, (f32x4*)(attb + (size_t)kg * NT));
    }
  }
}

// ---------------- out-projection + residual + GN partial sums (128², full chip) ----------------
__global__ __launch_bounds__(256) void k_outgemm(const unsigned short* __restrict__ Wo,
                                                 const unsigned short* __restrict__ ctxT,
                                                 const float* __restrict__ x,
                                                 float* __restrict__ y0,
                                                 float* __restrict__ partials) {
  __shared__ char lds[32832];
  const int tid = threadIdx.x, lane = tid & 63, wave = tid >> 6;
  const int wr = wave >> 1, wc = wave & 1;
  const int bm = blockIdx.x, bn = blockIdx.y, b = blockIdx.z;
  const unsigned short* A = Wo + (size_t)bm * 128 * NC;
  const unsigned short* Bt = ctxT + ((size_t)b * NT + (size_t)bn * 128) * NC;
  f32x4 acc[4][4];
  gemm_core_128<NC>(A, Bt, NC, NC, lds, tid, acc);

  float lsum = 0.f, lsq = 0.f;
#pragma unroll
  for (int mf = 0; mf < 4; ++mf) {
#pragma unroll
    for (int nf = 0; nf < 4; ++nf) {
      const int gc = bn * 128 + wc * 64 + nf * 16 + (lane & 15);
#pragma unroll
      for (int i = 0; i < 4; ++i) {
        const int gr = bm * 128 + wr * 64 + mf * 16 + ((lane >> 4) << 2) + i;
        const size_t idx = ((size_t)b * NC + gr) * NT + gc;
        const float v = acc[mf][nf][i] + x[idx];
        y0[idx] = v;
        lsum += v; lsq += v * v;
      }
    }
  }
#pragma unroll
  for (int off = 32; off; off >>= 1) {
    lsum += __shfl_xor(lsum, off);
    lsq += __shfl_xor(lsq, off);
  }
  __syncthreads();
  float* red = (float*)(lds + 32768);
  if (lane == 0) { red[wave * 2] = lsum; red[wave * 2 + 1] = lsq; }
  __syncthreads();
  if (tid == 0) {
    const float s = red[0] + red[2] + red[4] + red[6];
    const float qq = red[1] + red[3] + red[5] + red[7];
    const int bi = bm * 8 + bn;
    partials[((size_t)b * 64 + bi) * 2] = s;
    partials[((size_t)b * 64 + bi) * 2 + 1] = qq;
  }
}

__global__ void k_gnstats(const float* __restrict__ partials, float* __restrict__ gnp) {
  const int b = blockIdx.x, t = threadIdx.x;
  float s = partials[((size_t)b * 64 + t) * 2];
  float q = partials[((size_t)b * 64 + t) * 2 + 1];
#pragma unroll
  for (int off = 32; off; off >>= 1) {
    s += __shfl_xor(s, off);
    q += __shfl_xor(q, off);
  }
  if (t == 0) {
    const float n = 1048576.f;
    const float mean = s / n;
    const float var = q / n - mean * mean;
    gnp[b * 2] = mean;
    gnp[b * 2 + 1] = rsqrtf(var + 1e-5f);
  }
}

__global__ __launch_bounds__(256) void k_gnapply(const float* __restrict__ y0,
                                                 const float* __restrict__ gnp,
                                                 const float* __restrict__ gw,
                                                 const float* __restrict__ gb,
                                                 float* __restrict__ out) {
  const size_t n4 = (size_t)NB * NC * NT / 4;
  const size_t stride = (size_t)gridDim.x * blockDim.x;
  for (size_t i = (size_t)blockIdx.x * blockDim.x + threadIdx.x; i < n4; i += stride) {
    const size_t base = i * 4;
    const int b = (int)(base >> 20);
    const int c = (int)((base >> 10) & 1023);
    const f32x4 v = *(const f32x4*)(y0 + base);
    const float m = gnp[b * 2], r = gnp[b * 2 + 1];
    const float sw = gw[c] * r, sb = gb[c];
    f32x4 o;
#pragma unroll
    for (int j = 0; j < 4; ++j) o[j] = (v[j] - m) * sw + sb;
    *(f32x4*)(out + base) = o;
  }
}

extern "C" void kernel_launch(void* const* d_in, const int* in_sizes, int n_in,
                              void* d_out, int out_size, void* d_ws, size_t ws_size,
                              hipStream_t stream) {
  (void)in_sizes; (void)n_in; (void)out_size; (void)ws_size;
  const float* x     = (const float*)d_in[0];
  const int*   mask  = (const int*)d_in[1];
  const float* w_kvq = (const float*)d_in[2];
  const float* w_out = (const float*)d_in[3];
  const float* gnw   = (const float*)d_in[4];
  const float* gnb   = (const float*)d_in[5];
  float* outy = (float*)d_out;
  float* att  = outy + (size_t)NB * NC * NT;  // att_ret region of d_out

  char* ws = (char*)d_ws;
  unsigned short* wkvq_bf = (unsigned short*)(ws);             //  6,291,456 B
  unsigned short* wout_bf = (unsigned short*)(ws + 6291456);   //  2,097,152 B
  unsigned short* xT      = (unsigned short*)(ws + 8388608);   // 16,777,216 B
  unsigned short* ctxT    = xT;                                // alias: xT dead after gemm1
  unsigned short* kt      = (unsigned short*)(ws + 25165824);  // 16,777,216 B
  unsigned short* qt      = (unsigned short*)(ws + 41943040);  // 16,777,216 B
  float*          y0      = (float*)(ws + 25165824);           // alias kt+qt: dead after att
  unsigned short* vbuf    = (unsigned short*)(ws + 58720256);  // 16,777,216 B
  float*          part    = (float*)(ws + 76021760);           //      4,096 B
  float*          gnp     = (float*)(ws + 76025856);           //         64 B

  k_prep<<<2048, 256, 0, stream>>>(w_kvq, wkvq_bf, w_out, wout_bf);
  k_xT<<<dim3(32, 32, 8), dim3(32, 8), 0, stream>>>(x, xT);
  k_gemm1_256<<<384, 512, 0, stream>>>(wkvq_bf, xT, kt, qt, vbuf);
  k_att3<<<dim3(128, 16), 512, 0, stream>>>(kt, qt, vbuf, mask, att, ctxT);
  k_outgemm<<<dim3(8, 8, 8), 256, 0, stream>>>(wout_bf, ctxT, x, y0, part);
  k_gnstats<<<8, 64, 0, stream>>>(part, gnp);
  k_gnapply<<<4096, 256, 0, stream>>>(y0, gnp, gnw, gnb, outy);
}

// Round 11
// 344.011 us; speedup vs baseline: 1.6935x; 1.0987x over previous
//
#include <hip/hip_runtime.h>

#define DEVI __device__ __forceinline__

typedef __attribute__((ext_vector_type(8))) short s16x8;
typedef __attribute__((ext_vector_type(4))) float f32x4;
typedef __attribute__((ext_vector_type(4))) unsigned short u16x4;
typedef __attribute__((ext_vector_type(4))) int i32x4;

static constexpr int NB = 8;      // batch
static constexpr int NC = 1024;   // channels
static constexpr int NT = 1024;   // time
static constexpr int NH = 16;     // heads
static constexpr int ND = 64;     // head dim

DEVI unsigned short cvt_bf16(float f) {
  unsigned int u = __builtin_bit_cast(unsigned int, f);
  u += 0x7fffu + ((u >> 16) & 1u);
  return (unsigned short)(u >> 16);
}

DEVI float fexp2(float x) {
#if __has_builtin(__builtin_amdgcn_exp2f)
  return __builtin_amdgcn_exp2f(x);
#else
  return exp2f(x);
#endif
}

// Stage a ROWS x 64 bf16 tile (row-major global, ld elems/row) into LDS at byte
// offset loff. 128 B per LDS row. Linear LDS dest, XOR-16B-chunk swizzle applied
// on the GLOBAL source (m173 pattern). Issues exactly ROWS/32 VMEM ops/thread.
template<int ROWS>
DEVI void stage_tile(const unsigned short* g, int ld, char* lds, int loff, int tid) {
  const int wave = tid >> 6;
  const int lane = tid & 63;
#pragma unroll
  for (int r = 0; r < (ROWS >> 5); ++r) {
    const int row = r * 32 + wave * 8 + (lane >> 3);
    const int c  = lane & 7;
    const int cg = c ^ (row & 7);
    const char* src = (const char*)g + (size_t)row * ld * 2 + cg * 16;
    char* dst = lds + loff + (r * 32 + wave * 8) * 128;  // wave-uniform
    __builtin_amdgcn_global_load_lds((const __attribute__((address_space(1))) void*)src,
                                     (__attribute__((address_space(3))) void*)dst,
                                     16, 0, 0);
  }
}

// Fragment read for mfma_f32_16x16x32_bf16: lane holds A[row][ks*32+(lane>>4)*8 .. +8]
DEVI s16x8 frag_ld(const char* lds, int loff, int row, int ks, int lane) {
  const int chunk = (ks * 4 + (lane >> 4)) ^ (row & 7);
  return *(const s16x8*)(lds + loff + row * 128 + chunk * 16);
}

// 128x128 tile TN GEMM core (256 threads)
template<int KTOT>
DEVI void gemm_core_128(const unsigned short* A, const unsigned short* Bt,
                        int ldA, int ldB, char* lds, int tid, f32x4 acc[4][4]) {
  const int lane = tid & 63;
  const int wave = tid >> 6;
  const int wr = wave >> 1, wc = wave & 1;
#pragma unroll
  for (int i = 0; i < 4; ++i)
#pragma unroll
    for (int j = 0; j < 4; ++j)
      acc[i][j] = (f32x4){0.f, 0.f, 0.f, 0.f};
  for (int k0 = 0; k0 < KTOT; k0 += 64) {
    __syncthreads();
    stage_tile<128>(A + k0, ldA, lds, 0, tid);
    stage_tile<128>(Bt + k0, ldB, lds, 16384, tid);
    asm volatile("s_waitcnt vmcnt(0)" ::: "memory");
    __syncthreads();
#pragma unroll
    for (int ks = 0; ks < 2; ++ks) {
      s16x8 af[4], bfr[4];
#pragma unroll
      for (int mf = 0; mf < 4; ++mf)
        af[mf] = frag_ld(lds, 0, wr * 64 + mf * 16 + (lane & 15), ks, lane);
#pragma unroll
      for (int nf = 0; nf < 4; ++nf)
        bfr[nf] = frag_ld(lds, 16384, wc * 64 + nf * 16 + (lane & 15), ks, lane);
#pragma unroll
      for (int mf = 0; mf < 4; ++mf)
#pragma unroll
        for (int nf = 0; nf < 4; ++nf)
          acc[mf][nf] = __builtin_amdgcn_mfma_f32_16x16x32_bf16(af[mf], bfr[nf], acc[mf][nf], 0, 0, 0);
    }
  }
}

// ---------------- prep ----------------
__global__ __launch_bounds__(256) void k_prep(const float* __restrict__ wkvq,
                                              unsigned short* __restrict__ wkvq_bf,
                                              const float* __restrict__ wout,
                                              unsigned short* __restrict__ wout_bf) {
  const int n1 = 3 * NC * NC / 4, n2 = NC * NC / 4;
  const int stride = gridDim.x * blockDim.x;
  for (int i = blockIdx.x * blockDim.x + threadIdx.x; i < n1 + n2; i += stride) {
    const float* src = (i < n1) ? wkvq + (size_t)i * 4 : wout + (size_t)(i - n1) * 4;
    unsigned short* dst = (i < n1) ? wkvq_bf + (size_t)i * 4 : wout_bf + (size_t)(i - n1) * 4;
    f32x4 v = *(const f32x4*)src;
    u16x4 o;
#pragma unroll
    for (int j = 0; j < 4; ++j) o[j] = cvt_bf16(v[j]);
    *(u16x4*)dst = o;
  }
}

// x [B,C,T] f32 -> xT [B,T,C] bf16
__global__ void k_xT(const float* __restrict__ x, unsigned short* __restrict__ xT) {
  __shared__ float tl[32][33];
  const int bz = blockIdx.z;
  const int t0 = blockIdx.x * 32, c0 = blockIdx.y * 32;
  const int tx = threadIdx.x, ty = threadIdx.y;  // (32,8)
#pragma unroll
  for (int j = 0; j < 4; ++j)
    tl[ty + j * 8][tx] = x[((size_t)bz * NC + c0 + ty + j * 8) * NT + t0 + tx];
  __syncthreads();
#pragma unroll
  for (int j = 0; j < 4; ++j)
    xT[((size_t)bz * NT + t0 + ty + j * 8) * NC + c0 + tx] = cvt_bf16(tl[tx][ty + j * 8]);
}

// ---------------- QKV projection: 256x256 tile, BK=32, 4-slot ring, counted vmcnt ----------------
__global__ __launch_bounds__(512, 2) void k_gemm1_256(const unsigned short* __restrict__ W,
                                                      const unsigned short* __restrict__ xT,
                                                      unsigned short* __restrict__ kt,
                                                      unsigned short* __restrict__ qt,
                                                      unsigned short* __restrict__ vbuf) {
  __shared__ char lds[131072];
  const int tid = threadIdx.x, lane = tid & 63, wid = tid >> 6;
  const int wr = wid >> 2, wc = wid & 3;
  const int gid = blockIdx.x;
  const int wg = (gid & 7) * 48 + (gid >> 3);
  const int bn = wg / 12, bm = wg % 12;

  const int r = tid >> 2, ccc = tid & 3;
  const int cg = ccc ^ ((r ^ (r >> 2)) & 3);
  const unsigned short* srcA = W + (size_t)(bm * 256 + r) * NC + cg * 8;
  const unsigned short* srcB = xT + (size_t)(bn * 256 + r) * NC + cg * 8;

  auto stageA = [&](int t) {
    char* d = lds + (t & 3) * 32768 + wid * 1024;
    const unsigned short* s = srcA + t * 32;
    __builtin_amdgcn_global_load_lds((const __attribute__((address_space(1))) void*)s,
                                     (__attribute__((address_space(3))) void*)d, 16, 0, 0);
    __builtin_amdgcn_global_load_lds((const __attribute__((address_space(1))) void*)(s + 128 * NC),
                                     (__attribute__((address_space(3))) void*)(d + 8192), 16, 0, 0);
  };
  auto stageB = [&](int t) {
    char* d = lds + (t & 3) * 32768 + 16384 + wid * 1024;
    const unsigned short* s = srcB + t * 32;
    __builtin_amdgcn_global_load_lds((const __attribute__((address_space(1))) void*)s,
                                     (__attribute__((address_space(3))) void*)d, 16, 0, 0);
    __builtin_amdgcn_global_load_lds((const __attribute__((address_space(1))) void*)(s + 128 * NC),
                                     (__attribute__((address_space(3))) void*)(d + 8192), 16, 0, 0);
  };

  const int l15 = lane & 15, lg = lane >> 4;
  const int rA = wr * 128 + l15;
  const int offA = rA * 64 + (((lg ^ (rA ^ (rA >> 2))) & 3) << 4) + ((lg & ~3) << 4);
  const int rB = wc * 64 + l15;
  const int offB = 16384 + rB * 64 + (((lg ^ (rB ^ (rB >> 2))) & 3) << 4) + ((lg & ~3) << 4);

  f32x4 acc[8][4];
#pragma unroll
  for (int i = 0; i < 8; ++i)
#pragma unroll
    for (int j = 0; j < 4; ++j) acc[i][j] = (f32x4){0.f, 0.f, 0.f, 0.f};

  stageA(0); stageB(0); stageA(1); stageB(1); stageA(2); stageB(2);
  asm volatile("s_waitcnt vmcnt(8)" ::: "memory");
  __builtin_amdgcn_s_barrier();

#pragma unroll
  for (int t = 0; t < 32; ++t) {
    const int slot = (t & 3) * 32768;
    s16x8 af[8], bf[4];
#pragma unroll
    for (int nf = 0; nf < 4; ++nf) bf[nf] = *(const s16x8*)(lds + slot + offB + nf * 1024);
#pragma unroll
    for (int mf = 0; mf < 4; ++mf) af[mf] = *(const s16x8*)(lds + slot + offA + mf * 1024);
    if (t < 29) stageA(t + 3);
    __builtin_amdgcn_s_barrier();
    asm volatile("s_waitcnt lgkmcnt(0)" ::: "memory");
    __builtin_amdgcn_sched_barrier(0);
    __builtin_amdgcn_s_setprio(1);
#pragma unroll
    for (int mf = 0; mf < 4; ++mf)
#pragma unroll
      for (int nf = 0; nf < 4; ++nf)
        acc[mf][nf] = __builtin_amdgcn_mfma_f32_16x16x32_bf16(af[mf], bf[nf], acc[mf][nf], 0, 0, 0);
    __builtin_amdgcn_s_setprio(0);
    __builtin_amdgcn_s_barrier();
#pragma unroll
    for (int mf = 4; mf < 8; ++mf) af[mf] = *(const s16x8*)(lds + slot + offA + mf * 1024);
    if (t < 29) stageB(t + 3);
    if (t < 29)       asm volatile("s_waitcnt vmcnt(8)" ::: "memory");
    else if (t == 29) asm volatile("s_waitcnt vmcnt(4)" ::: "memory");
    else              asm volatile("s_waitcnt vmcnt(0)" ::: "memory");
    __builtin_amdgcn_s_barrier();
    asm volatile("s_waitcnt lgkmcnt(0)" ::: "memory");
    __builtin_amdgcn_sched_barrier(0);
    __builtin_amdgcn_s_setprio(1);
#pragma unroll
    for (int mf = 4; mf < 8; ++mf)
#pragma unroll
      for (int nf = 0; nf < 4; ++nf)
        acc[mf][nf] = __builtin_amdgcn_mfma_f32_16x16x32_bf16(af[mf], bf[nf], acc[mf][nf], 0, 0, 0);
    __builtin_amdgcn_s_setprio(0);
    __builtin_amdgcn_s_barrier();
  }

  const int part = bm >> 2;
  const int d0base = lg << 2;
#pragma unroll
  for (int mf = 0; mf < 8; ++mf) {
    const int h = ((bm & 3) << 2) + (wr << 1) + (mf >> 2);
    const int d0 = ((mf & 3) << 4) + d0base;
#pragma unroll
    for (int nf = 0; nf < 4; ++nf) {
      const int tg = bn * 256 + wc * 64 + nf * 16 + l15;
      const int b = tg >> 10, tt = tg & 1023;
      u16x4 v4;
#pragma unroll
      for (int i = 0; i < 4; ++i) v4[i] = cvt_bf16(acc[mf][nf][i]);
      if (part == 0) {
        *(u16x4*)(kt + (((size_t)(b * NH + h) * NT + tt) * ND + d0)) = v4;
      } else if (part == 1) {
        const size_t basev = ((size_t)(b * NH + h) * ND + d0) * NT + tt;
        vbuf[basev] = v4[0]; vbuf[basev + NT] = v4[1];
        vbuf[basev + 2 * NT] = v4[2]; vbuf[basev + 3 * NT] = v4[3];
      } else {
        *(u16x4*)(qt + (((size_t)(b * NH + h) * NT + tt) * ND + d0)) = v4;
      }
    }
  }
}

// ---------------- merged attention: r7 two-pass schedule, k-tile 64, 33 KB LDS ----------------
// 256 threads, 4 waves: wr=wave>>1 (k-32-half), wc=wave&1 (q-64-half). q-tile 128.
// LDS: K dbuf 2x8K (KOFF/VOFF), P(=Q at init) 16K, colacc/mbits. 3-4 blocks/CU.
// Pass 1: colsum (K dbuf KOFF/VOFF, counted vmcnt(2)).
// Pass 2: per k-tile: QK -> barrier -> stageK(t+1) -> normalized att stores (8x dwordx4,
//   kept in flight via counted vmcnt) + P^T relay -> PV -> stageV(t+1).
__global__ __launch_bounds__(256, 3) void k_att(const unsigned short* __restrict__ kt,
                                                const unsigned short* __restrict__ qt,
                                                const unsigned short* __restrict__ vbuf,
                                                const int* __restrict__ mask,
                                                float* __restrict__ att,
                                                unsigned short* __restrict__ ctxT) {
  __shared__ char lds[33408];
  constexpr int KOFF = 0, VOFF = 8192, POFF = 16384, COFF = 32768;
  float* colacc = (float*)(lds + COFF);                                 // 128 f32
  unsigned long long* mbits = (unsigned long long*)(lds + COFF + 512);  // 16 u64
  const int tid = threadIdx.x, lane = tid & 63, wave = tid >> 6;
  const int wr = wave >> 1, wc = wave & 1;
  const int bh = blockIdx.x, qb = blockIdx.y;   // x=bh so q-replicas share an XCD
  const int b = bh >> 4, h = bh & 15, hb = h * NB + b;
  const int q0 = qb * 128;
  const unsigned short* ktp = kt + (size_t)bh * NT * ND;
  const unsigned short* qtp = qt + ((size_t)bh * NT + q0) * ND;
  const unsigned short* vp  = vbuf + (size_t)bh * ND * NT;
  const int l15 = lane & 15, g = lane >> 4;

  if (tid < 128) colacc[tid] = 0.f;
  stage_tile<128>(qtp, ND, lds, POFF, tid);     // Q parked in P region
#pragma unroll
  for (int j = 0; j < 4; ++j) {
    unsigned long long bb = __ballot(mask[b * NT + wave * 256 + j * 64 + lane] != 0);
    if (lane == 0) mbits[wave * 4 + j] = bb;
  }
  i32x4 qm4[4];
#pragma unroll
  for (int nf = 0; nf < 4; ++nf)
    qm4[nf] = *(const i32x4*)(mask + b * NT + q0 + wc * 64 + nf * 16 + g * 4);
  asm volatile("s_waitcnt vmcnt(0)" ::: "memory");
  __syncthreads();   // Q + mbits resident; vmcnt exactly 0

  s16x8 qf[4][2];
#pragma unroll
  for (int nf = 0; nf < 4; ++nf)
#pragma unroll
    for (int ks = 0; ks < 2; ++ks)
      qf[nf][ks] = frag_ld(lds, POFF, wc * 64 + nf * 16 + l15, ks, lane);
  __syncthreads();   // all waves have Q in regs; P region reusable

  // per-thread k-mask: bit (t*2+mf) for k = t*64 + wr*32 + mf*16 + l15
  unsigned int kmask32 = 0;
#pragma unroll
  for (int t = 0; t < 16; ++t) {
    const unsigned long long w64 = mbits[t];
#pragma unroll
    for (int mf = 0; mf < 2; ++mf)
      kmask32 |= (unsigned int)((w64 >> (wr * 32 + mf * 16 + l15)) & 1ull) << (t * 2 + mf);
  }

  const float scl = 0.125f * 1.44269504f;  // scale * log2(e)

  // ---- pass 1: denominators (K dbuf KOFF/VOFF, counted vmcnt(2)) ----
  f32x4 cs4[4];
#pragma unroll
  for (int nf = 0; nf < 4; ++nf) cs4[nf] = (f32x4){0.f, 0.f, 0.f, 0.f};
  stage_tile<64>(ktp, ND, lds, KOFF, tid);
  for (int t = 0; t < 16; ++t) {
    __builtin_amdgcn_s_barrier();
    if (t < 15) {
      stage_tile<64>(ktp + (size_t)(t + 1) * 64 * ND, ND, lds, (t & 1) ? KOFF : VOFF, tid);
      asm volatile("s_waitcnt vmcnt(2)" ::: "memory");   // tile t resident
    } else {
      asm volatile("s_waitcnt vmcnt(0)" ::: "memory");
    }
    __builtin_amdgcn_s_barrier();
    const int koff = (t & 1) ? VOFF : KOFF;
    f32x4 sacc[2][4];
#pragma unroll
    for (int i = 0; i < 2; ++i)
#pragma unroll
      for (int j = 0; j < 4; ++j) sacc[i][j] = (f32x4){0.f, 0.f, 0.f, 0.f};
#pragma unroll
    for (int ks = 0; ks < 2; ++ks) {
      s16x8 kf[2];
#pragma unroll
      for (int mf = 0; mf < 2; ++mf)
        kf[mf] = frag_ld(lds, koff, wr * 32 + mf * 16 + l15, ks, lane);
#pragma unroll
      for (int mf = 0; mf < 2; ++mf)
#pragma unroll
        for (int nf = 0; nf < 4; ++nf)
          sacc[mf][nf] = __builtin_amdgcn_mfma_f32_16x16x32_bf16(qf[nf][ks], kf[mf], sacc[mf][nf], 0, 0, 0);
    }
#pragma unroll
    for (int mf = 0; mf < 2; ++mf) {
      const float kz = ((kmask32 >> (t * 2 + mf)) & 1u) ? 0.f : 1.f;
#pragma unroll
      for (int nf = 0; nf < 4; ++nf)
#pragma unroll
        for (int i = 0; i < 4; ++i)
          cs4[nf][i] += kz * fexp2(sacc[mf][nf][i] * scl);
    }
  }
  // reduce over 16 lanes (k) per group, then atomic-combine wr halves
#pragma unroll
  for (int nf = 0; nf < 4; ++nf)
#pragma unroll
    for (int i = 0; i < 4; ++i) {
      float v = cs4[nf][i];
      v += __shfl_xor(v, 1); v += __shfl_xor(v, 2);
      v += __shfl_xor(v, 4); v += __shfl_xor(v, 8);
      cs4[nf][i] = v;
    }
  if (l15 == 0) {
#pragma unroll
    for (int nf = 0; nf < 4; ++nf)
#pragma unroll
      for (int i = 0; i < 4; ++i)
        atomicAdd(&colacc[wc * 64 + nf * 16 + g * 4 + i], cs4[nf][i]);
  }
  __syncthreads();
  f32x4 sq4[4];
#pragma unroll
  for (int nf = 0; nf < 4; ++nf)
#pragma unroll
    for (int i = 0; i < 4; ++i)
      sq4[nf][i] = qm4[nf][i] ? 0.f : 1.0f / colacc[wc * 64 + nf * 16 + g * 4 + i];

  // ---- pass 2: att write + PV, stores kept in flight (counted vmcnt) ----
  f32x4 cacc[4][2];
#pragma unroll
  for (int i = 0; i < 4; ++i)
#pragma unroll
    for (int j = 0; j < 2; ++j) cacc[i][j] = (f32x4){0.f, 0.f, 0.f, 0.f};

  stage_tile<64>(ktp, ND, lds, KOFF, tid);       // 2 ops
  stage_tile<64>(vp, NT, lds, VOFF, tid);        // 2 ops (V rows d, stride NT)
  asm volatile("s_waitcnt vmcnt(0)" ::: "memory");
  __builtin_amdgcn_s_barrier();

  float* attb = att + (size_t)hb * NT * NT + q0 + wc * 64 + g * 4;
  for (int t = 0; t < 16; ++t) {
    // QK(t) reads KOFF
    f32x4 sacc[2][4];
#pragma unroll
    for (int i = 0; i < 2; ++i)
#pragma unroll
      for (int j = 0; j < 4; ++j) sacc[i][j] = (f32x4){0.f, 0.f, 0.f, 0.f};
#pragma unroll
    for (int ks = 0; ks < 2; ++ks) {
      s16x8 kf[2];
#pragma unroll
      for (int mf = 0; mf < 2; ++mf)
        kf[mf] = frag_ld(lds, KOFF, wr * 32 + mf * 16 + l15, ks, lane);
#pragma unroll
      for (int mf = 0; mf < 2; ++mf)
#pragma unroll
        for (int nf = 0; nf < 4; ++nf)
          sacc[mf][nf] = __builtin_amdgcn_mfma_f32_16x16x32_bf16(qf[nf][ks], kf[mf], sacc[mf][nf], 0, 0, 0);
    }
    __builtin_amdgcn_s_barrier();                 // KOFF free
    if (t < 15) stage_tile<64>(ktp + (size_t)(t + 1) * 64 * ND, ND, lds, KOFF, tid);  // 2 ops
    __builtin_amdgcn_sched_barrier(0);            // pin: stageK before stores

    // epilogue: p4 = kz * exp * sq (8x dwordx4 att stores) + P^T bf16 -> LDS
#pragma unroll
    for (int mf = 0; mf < 2; ++mf) {
      const int kg = t * 64 + wr * 32 + mf * 16 + l15;
      const float kz = ((kmask32 >> (t * 2 + mf)) & 1u) ? 0.f : 1.f;
      const int kloc = wr * 32 + mf * 16 + l15;
#pragma unroll
      for (int nf = 0; nf < 4; ++nf) {
        f32x4 p4;
#pragma unroll
        for (int i = 0; i < 4; ++i)
          p4[i] = kz * fexp2(sacc[mf][nf][i] * scl) * sq4[nf][i];
        __builtin_nontemporal_store(p4, (f32x4*)(attb + (size_t)kg * NT + nf * 16));
        const int qrow = wc * 64 + nf * 16 + g * 4;
#pragma unroll
        for (int i = 0; i < 4; ++i) {
          const int row = qrow + i;
          *(unsigned short*)(lds + POFF + row * 128 + (((kloc >> 3) ^ (row & 7)) << 4)
                             + ((kloc & 7) << 1)) = cvt_bf16(p4[i]);
        }
      }
    }
    asm volatile("s_waitcnt lgkmcnt(0)" ::: "memory");  // P^T visible (NOT the att stores)
    __builtin_amdgcn_sched_barrier(0);
    __builtin_amdgcn_s_barrier();
    // V(t) resident: FIFO [stageV(t)2, stageK(t+1)2, stores(t)8] -> keep 10; tail keeps 8
    if (t < 15) asm volatile("s_waitcnt vmcnt(10)" ::: "memory");
    else        asm volatile("s_waitcnt vmcnt(8)" ::: "memory");

    // PV(t): ctx[d][q] += V[d][k] * P[k][q]; wave covers q = wave*32..+31
#pragma unroll
    for (int ks2 = 0; ks2 < 2; ++ks2) {
      s16x8 vf[4], pf[2];
#pragma unroll
      for (int mf = 0; mf < 4; ++mf)
        vf[mf] = frag_ld(lds, VOFF, mf * 16 + l15, ks2, lane);
#pragma unroll
      for (int nf2 = 0; nf2 < 2; ++nf2)
        pf[nf2] = frag_ld(lds, POFF, wave * 32 + nf2 * 16 + l15, ks2, lane);
#pragma unroll
      for (int mf = 0; mf < 4; ++mf)
#pragma unroll
        for (int nf2 = 0; nf2 < 2; ++nf2)
          cacc[mf][nf2] = __builtin_amdgcn_mfma_f32_16x16x32_bf16(vf[mf], pf[nf2], cacc[mf][nf2], 0, 0, 0);
    }
    __builtin_amdgcn_s_barrier();                 // VOFF/POFF free
    if (t < 15) {
      stage_tile<64>(vp + (t + 1) * 64, NT, lds, VOFF, tid);   // 2 ops
      // K(t+1) resident: FIFO [stageK(t+1)2, stores(t)8, stageV(t+1)2] -> keep 10
      asm volatile("s_waitcnt vmcnt(10)" ::: "memory");
      __builtin_amdgcn_s_barrier();
    }
  }

  // ctx epilogue: ctxT[b][q][h*64+d]
#pragma unroll
  for (int mf = 0; mf < 4; ++mf) {
    const int d0 = mf * 16 + (g << 2);
#pragma unroll
    for (int nf2 = 0; nf2 < 2; ++nf2) {
      const int q = q0 + wave * 32 + nf2 * 16 + l15;
      u16x4 v4;
#pragma unroll
      for (int i = 0; i < 4; ++i) v4[i] = cvt_bf16(cacc[mf][nf2][i]);
      *(u16x4*)(ctxT + ((size_t)b * NT + q) * NC + h * ND + d0) = v4;
    }
  }
}

// ---------------- out-projection + residual + GN partial sums (128², full chip) ----------------
__global__ __launch_bounds__(256) void k_outgemm(const unsigned short* __restrict__ Wo,
                                                 const unsigned short* __restrict__ ctxT,
                                                 const float* __restrict__ x,
                                                 float* __restrict__ y0,
                                                 float* __restrict__ partials) {
  __shared__ char lds[32832];
  const int tid = threadIdx.x, lane = tid & 63, wave = tid >> 6;
  const int wr = wave >> 1, wc = wave & 1;
  const int bm = blockIdx.x, bn = blockIdx.y, b = blockIdx.z;
  const unsigned short* A = Wo + (size_t)bm * 128 * NC;
  const unsigned short* Bt = ctxT + ((size_t)b * NT + (size_t)bn * 128) * NC;
  f32x4 acc[4][4];
  gemm_core_128<NC>(A, Bt, NC, NC, lds, tid, acc);

  float lsum = 0.f, lsq = 0.f;
#pragma unroll
  for (int mf = 0; mf < 4; ++mf) {
#pragma unroll
    for (int nf = 0; nf < 4; ++nf) {
      const int gc = bn * 128 + wc * 64 + nf * 16 + (lane & 15);
#pragma unroll
      for (int i = 0; i < 4; ++i) {
        const int gr = bm * 128 + wr * 64 + mf * 16 + ((lane >> 4) << 2) + i;
        const size_t idx = ((size_t)b * NC + gr) * NT + gc;
        const float v = acc[mf][nf][i] + x[idx];
        y0[idx] = v;
        lsum += v; lsq += v * v;
      }
    }
  }
#pragma unroll
  for (int off = 32; off; off >>= 1) {
    lsum += __shfl_xor(lsum, off);
    lsq += __shfl_xor(lsq, off);
  }
  __syncthreads();
  float* red = (float*)(lds + 32768);
  if (lane == 0) { red[wave * 2] = lsum; red[wave * 2 + 1] = lsq; }
  __syncthreads();
  if (tid == 0) {
    const float s = red[0] + red[2] + red[4] + red[6];
    const float qq = red[1] + red[3] + red[5] + red[7];
    const int bi = bm * 8 + bn;
    partials[((size_t)b * 64 + bi) * 2] = s;
    partials[((size_t)b * 64 + bi) * 2 + 1] = qq;
  }
}

__global__ void k_gnstats(const float* __restrict__ partials, float* __restrict__ gnp) {
  const int b = blockIdx.x, t = threadIdx.x;
  float s = partials[((size_t)b * 64 + t) * 2];
  float q = partials[((size_t)b * 64 + t) * 2 + 1];
#pragma unroll
  for (int off = 32; off; off >>= 1) {
    s += __shfl_xor(s, off);
    q += __shfl_xor(q, off);
  }
  if (t == 0) {
    const float n = 1048576.f;
    const float mean = s / n;
    const float var = q / n - mean * mean;
    gnp[b * 2] = mean;
    gnp[b * 2 + 1] = rsqrtf(var + 1e-5f);
  }
}

__global__ __launch_bounds__(256) void k_gnapply(const float* __restrict__ y0,
                                                 const float* __restrict__ gnp,
                                                 const float* __restrict__ gw,
                                                 const float* __restrict__ gb,
                                                 float* __restrict__ out) {
  const size_t n4 = (size_t)NB * NC * NT / 4;
  const size_t stride = (size_t)gridDim.x * blockDim.x;
  for (size_t i = (size_t)blockIdx.x * blockDim.x + threadIdx.x; i < n4; i += stride) {
    const size_t base = i * 4;
    const int b = (int)(base >> 20);
    const int c = (int)((base >> 10) & 1023);
    const f32x4 v = *(const f32x4*)(y0 + base);
    const float m = gnp[b * 2], r = gnp[b * 2 + 1];
    const float sw = gw[c] * r, sb = gb[c];
    f32x4 o;
#pragma unroll
    for (int j = 0; j < 4; ++j) o[j] = (v[j] - m) * sw + sb;
    *(f32x4*)(out + base) = o;
  }
}

extern "C" void kernel_launch(void* const* d_in, const int* in_sizes, int n_in,
                              void* d_out, int out_size, void* d_ws, size_t ws_size,
                              hipStream_t stream) {
  (void)in_sizes; (void)n_in; (void)out_size; (void)ws_size;
  const float* x     = (const float*)d_in[0];
  const int*   mask  = (const int*)d_in[1];
  const float* w_kvq = (const float*)d_in[2];
  const float* w_out = (const float*)d_in[3];
  const float* gnw   = (const float*)d_in[4];
  const float* gnb   = (const float*)d_in[5];
  float* outy = (float*)d_out;
  float* att  = outy + (size_t)NB * NC * NT;  // att_ret region of d_out

  char* ws = (char*)d_ws;
  unsigned short* wkvq_bf = (unsigned short*)(ws);             //  6,291,456 B
  unsigned short* wout_bf = (unsigned short*)(ws + 6291456);   //  2,097,152 B
  unsigned short* xT      = (unsigned short*)(ws + 8388608);   // 16,777,216 B
  unsigned short* ctxT    = xT;                                // alias: xT dead after gemm1
  unsigned short* kt      = (unsigned short*)(ws + 25165824);  // 16,777,216 B
  unsigned short* qt      = (unsigned short*)(ws + 41943040);  // 16,777,216 B
  float*          y0      = (float*)(ws + 25165824);           // alias kt+qt: dead after att
  unsigned short* vbuf    = (unsigned short*)(ws + 58720256);  // 16,777,216 B
  float*          part    = (float*)(ws + 76021760);           //      4,096 B
  float*          gnp     = (float*)(ws + 76025856);           //         64 B

  k_prep<<<2048, 256, 0, stream>>>(w_kvq, wkvq_bf, w_out, wout_bf);
  k_xT<<<dim3(32, 32, 8), dim3(32, 8), 0, stream>>>(x, xT);
  k_gemm1_256<<<384, 512, 0, stream>>>(wkvq_bf, xT, kt, qt, vbuf);
  k_att<<<dim3(128, 8), 256, 0, stream>>>(kt, qt, vbuf, mask, att, ctxT);
  k_outgemm<<<dim3(8, 8, 8), 256, 0, stream>>>(wout_bf, ctxT, x, y0, part);
  k_gnstats<<<8, 64, 0, stream>>>(part, gnp);
  k_gnapply<<<4096, 256, 0, stream>>>(y0, gnp, gnw, gnb, outy);
}

// Round 12
// 279.341 us; speedup vs baseline: 2.0855x; 1.2315x over previous
//
#include <hip/hip_runtime.h>

#define DEVI __device__ __forceinline__

typedef __attribute__((ext_vector_type(8))) short s16x8;
typedef __attribute__((ext_vector_type(4))) float f32x4;
typedef __attribute__((ext_vector_type(4))) unsigned short u16x4;
typedef __attribute__((ext_vector_type(4))) int i32x4;

static constexpr int NB = 8;      // batch
static constexpr int NC = 1024;   // channels
static constexpr int NT = 1024;   // time
static constexpr int NH = 16;     // heads
static constexpr int ND = 64;     // head dim

DEVI unsigned short cvt_bf16(float f) {
  unsigned int u = __builtin_bit_cast(unsigned int, f);
  u += 0x7fffu + ((u >> 16) & 1u);
  return (unsigned short)(u >> 16);
}

DEVI float fexp2(float x) {
#if __has_builtin(__builtin_amdgcn_exp2f)
  return __builtin_amdgcn_exp2f(x);
#else
  return exp2f(x);
#endif
}

// Stage a ROWS x 64 bf16 tile (row-major global, ld elems/row) into LDS at byte
// offset loff. 128 B per LDS row. Linear LDS dest, XOR-16B-chunk swizzle applied
// on the GLOBAL source (m173 pattern). Issues exactly ROWS/32 VMEM ops/thread.
template<int ROWS>
DEVI void stage_tile(const unsigned short* g, int ld, char* lds, int loff, int tid) {
  const int wave = tid >> 6;
  const int lane = tid & 63;
#pragma unroll
  for (int r = 0; r < (ROWS >> 5); ++r) {
    const int row = r * 32 + wave * 8 + (lane >> 3);
    const int c  = lane & 7;
    const int cg = c ^ (row & 7);
    const char* src = (const char*)g + (size_t)row * ld * 2 + cg * 16;
    char* dst = lds + loff + (r * 32 + wave * 8) * 128;  // wave-uniform
    __builtin_amdgcn_global_load_lds((const __attribute__((address_space(1))) void*)src,
                                     (__attribute__((address_space(3))) void*)dst,
                                     16, 0, 0);
  }
}

// Fragment read for mfma_f32_16x16x32_bf16: lane holds A[row][ks*32+(lane>>4)*8 .. +8]
DEVI s16x8 frag_ld(const char* lds, int loff, int row, int ks, int lane) {
  const int chunk = (ks * 4 + (lane >> 4)) ^ (row & 7);
  return *(const s16x8*)(lds + loff + row * 128 + chunk * 16);
}

// 128x128 tile TN GEMM core (256 threads)
template<int KTOT>
DEVI void gemm_core_128(const unsigned short* A, const unsigned short* Bt,
                        int ldA, int ldB, char* lds, int tid, f32x4 acc[4][4]) {
  const int lane = tid & 63;
  const int wave = tid >> 6;
  const int wr = wave >> 1, wc = wave & 1;
#pragma unroll
  for (int i = 0; i < 4; ++i)
#pragma unroll
    for (int j = 0; j < 4; ++j)
      acc[i][j] = (f32x4){0.f, 0.f, 0.f, 0.f};
  for (int k0 = 0; k0 < KTOT; k0 += 64) {
    __syncthreads();
    stage_tile<128>(A + k0, ldA, lds, 0, tid);
    stage_tile<128>(Bt + k0, ldB, lds, 16384, tid);
    asm volatile("s_waitcnt vmcnt(0)" ::: "memory");
    __syncthreads();
#pragma unroll
    for (int ks = 0; ks < 2; ++ks) {
      s16x8 af[4], bfr[4];
#pragma unroll
      for (int mf = 0; mf < 4; ++mf)
        af[mf] = frag_ld(lds, 0, wr * 64 + mf * 16 + (lane & 15), ks, lane);
#pragma unroll
      for (int nf = 0; nf < 4; ++nf)
        bfr[nf] = frag_ld(lds, 16384, wc * 64 + nf * 16 + (lane & 15), ks, lane);
#pragma unroll
      for (int mf = 0; mf < 4; ++mf)
#pragma unroll
        for (int nf = 0; nf < 4; ++nf)
          acc[mf][nf] = __builtin_amdgcn_mfma_f32_16x16x32_bf16(af[mf], bfr[nf], acc[mf][nf], 0, 0, 0);
    }
  }
}

// ---------------- prep ----------------
__global__ __launch_bounds__(256) void k_prep(const float* __restrict__ wkvq,
                                              unsigned short* __restrict__ wkvq_bf,
                                              const float* __restrict__ wout,
                                              unsigned short* __restrict__ wout_bf) {
  const int n1 = 3 * NC * NC / 4, n2 = NC * NC / 4;
  const int stride = gridDim.x * blockDim.x;
  for (int i = blockIdx.x * blockDim.x + threadIdx.x; i < n1 + n2; i += stride) {
    const float* src = (i < n1) ? wkvq + (size_t)i * 4 : wout + (size_t)(i - n1) * 4;
    unsigned short* dst = (i < n1) ? wkvq_bf + (size_t)i * 4 : wout_bf + (size_t)(i - n1) * 4;
    f32x4 v = *(const f32x4*)src;
    u16x4 o;
#pragma unroll
    for (int j = 0; j < 4; ++j) o[j] = cvt_bf16(v[j]);
    *(u16x4*)dst = o;
  }
}

// x [B,C,T] f32 -> xT [B,T,C] bf16
__global__ void k_xT(const float* __restrict__ x, unsigned short* __restrict__ xT) {
  __shared__ float tl[32][33];
  const int bz = blockIdx.z;
  const int t0 = blockIdx.x * 32, c0 = blockIdx.y * 32;
  const int tx = threadIdx.x, ty = threadIdx.y;  // (32,8)
#pragma unroll
  for (int j = 0; j < 4; ++j)
    tl[ty + j * 8][tx] = x[((size_t)bz * NC + c0 + ty + j * 8) * NT + t0 + tx];
  __syncthreads();
#pragma unroll
  for (int j = 0; j < 4; ++j)
    xT[((size_t)bz * NT + t0 + ty + j * 8) * NC + c0 + tx] = cvt_bf16(tl[tx][ty + j * 8]);
}

// ---------------- QKV projection: 256x256 tile, BK=32, 4-slot ring, counted vmcnt ----------------
__global__ __launch_bounds__(512, 2) void k_gemm1_256(const unsigned short* __restrict__ W,
                                                      const unsigned short* __restrict__ xT,
                                                      unsigned short* __restrict__ kt,
                                                      unsigned short* __restrict__ qt,
                                                      unsigned short* __restrict__ vbuf) {
  __shared__ char lds[131072];
  const int tid = threadIdx.x, lane = tid & 63, wid = tid >> 6;
  const int wr = wid >> 2, wc = wid & 3;
  const int gid = blockIdx.x;
  const int wg = (gid & 7) * 48 + (gid >> 3);
  const int bn = wg / 12, bm = wg % 12;

  const int r = tid >> 2, ccc = tid & 3;
  const int cg = ccc ^ ((r ^ (r >> 2)) & 3);
  const unsigned short* srcA = W + (size_t)(bm * 256 + r) * NC + cg * 8;
  const unsigned short* srcB = xT + (size_t)(bn * 256 + r) * NC + cg * 8;

  auto stageA = [&](int t) {
    char* d = lds + (t & 3) * 32768 + wid * 1024;
    const unsigned short* s = srcA + t * 32;
    __builtin_amdgcn_global_load_lds((const __attribute__((address_space(1))) void*)s,
                                     (__attribute__((address_space(3))) void*)d, 16, 0, 0);
    __builtin_amdgcn_global_load_lds((const __attribute__((address_space(1))) void*)(s + 128 * NC),
                                     (__attribute__((address_space(3))) void*)(d + 8192), 16, 0, 0);
  };
  auto stageB = [&](int t) {
    char* d = lds + (t & 3) * 32768 + 16384 + wid * 1024;
    const unsigned short* s = srcB + t * 32;
    __builtin_amdgcn_global_load_lds((const __attribute__((address_space(1))) void*)s,
                                     (__attribute__((address_space(3))) void*)d, 16, 0, 0);
    __builtin_amdgcn_global_load_lds((const __attribute__((address_space(1))) void*)(s + 128 * NC),
                                     (__attribute__((address_space(3))) void*)(d + 8192), 16, 0, 0);
  };

  const int l15 = lane & 15, lg = lane >> 4;
  const int rA = wr * 128 + l15;
  const int offA = rA * 64 + (((lg ^ (rA ^ (rA >> 2))) & 3) << 4) + ((lg & ~3) << 4);
  const int rB = wc * 64 + l15;
  const int offB = 16384 + rB * 64 + (((lg ^ (rB ^ (rB >> 2))) & 3) << 4) + ((lg & ~3) << 4);

  f32x4 acc[8][4];
#pragma unroll
  for (int i = 0; i < 8; ++i)
#pragma unroll
    for (int j = 0; j < 4; ++j) acc[i][j] = (f32x4){0.f, 0.f, 0.f, 0.f};

  stageA(0); stageB(0); stageA(1); stageB(1); stageA(2); stageB(2);
  asm volatile("s_waitcnt vmcnt(8)" ::: "memory");
  __builtin_amdgcn_s_barrier();

#pragma unroll
  for (int t = 0; t < 32; ++t) {
    const int slot = (t & 3) * 32768;
    s16x8 af[8], bf[4];
#pragma unroll
    for (int nf = 0; nf < 4; ++nf) bf[nf] = *(const s16x8*)(lds + slot + offB + nf * 1024);
#pragma unroll
    for (int mf = 0; mf < 4; ++mf) af[mf] = *(const s16x8*)(lds + slot + offA + mf * 1024);
    if (t < 29) stageA(t + 3);
    __builtin_amdgcn_s_barrier();
    asm volatile("s_waitcnt lgkmcnt(0)" ::: "memory");
    __builtin_amdgcn_sched_barrier(0);
    __builtin_amdgcn_s_setprio(1);
#pragma unroll
    for (int mf = 0; mf < 4; ++mf)
#pragma unroll
      for (int nf = 0; nf < 4; ++nf)
        acc[mf][nf] = __builtin_amdgcn_mfma_f32_16x16x32_bf16(af[mf], bf[nf], acc[mf][nf], 0, 0, 0);
    __builtin_amdgcn_s_setprio(0);
    __builtin_amdgcn_s_barrier();
#pragma unroll
    for (int mf = 4; mf < 8; ++mf) af[mf] = *(const s16x8*)(lds + slot + offA + mf * 1024);
    if (t < 29) stageB(t + 3);
    if (t < 29)       asm volatile("s_waitcnt vmcnt(8)" ::: "memory");
    else if (t == 29) asm volatile("s_waitcnt vmcnt(4)" ::: "memory");
    else              asm volatile("s_waitcnt vmcnt(0)" ::: "memory");
    __builtin_amdgcn_s_barrier();
    asm volatile("s_waitcnt lgkmcnt(0)" ::: "memory");
    __builtin_amdgcn_sched_barrier(0);
    __builtin_amdgcn_s_setprio(1);
#pragma unroll
    for (int mf = 4; mf < 8; ++mf)
#pragma unroll
      for (int nf = 0; nf < 4; ++nf)
        acc[mf][nf] = __builtin_amdgcn_mfma_f32_16x16x32_bf16(af[mf], bf[nf], acc[mf][nf], 0, 0, 0);
    __builtin_amdgcn_s_setprio(0);
    __builtin_amdgcn_s_barrier();
  }

  const int part = bm >> 2;
  const int d0base = lg << 2;
#pragma unroll
  for (int mf = 0; mf < 8; ++mf) {
    const int h = ((bm & 3) << 2) + (wr << 1) + (mf >> 2);
    const int d0 = ((mf & 3) << 4) + d0base;
#pragma unroll
    for (int nf = 0; nf < 4; ++nf) {
      const int tg = bn * 256 + wc * 64 + nf * 16 + l15;
      const int b = tg >> 10, tt = tg & 1023;
      u16x4 v4;
#pragma unroll
      for (int i = 0; i < 4; ++i) v4[i] = cvt_bf16(acc[mf][nf][i]);
      if (part == 0) {
        *(u16x4*)(kt + (((size_t)(b * NH + h) * NT + tt) * ND + d0)) = v4;
      } else if (part == 1) {
        const size_t basev = ((size_t)(b * NH + h) * ND + d0) * NT + tt;
        vbuf[basev] = v4[0]; vbuf[basev + NT] = v4[1];
        vbuf[basev + 2 * NT] = v4[2]; vbuf[basev + 3 * NT] = v4[3];
      } else {
        *(u16x4*)(qt + (((size_t)(b * NH + h) * NT + tt) * ND + d0)) = v4;
      }
    }
  }
}

// ---------------- merged attention: two-pass, k-tile 64, row-contiguous att stores ----------------
// 256 threads, 4 waves: wr=wave>>1 (k-32-half), wc=wave&1 (q-64-half). q-tile 128.
// LDS: K dbuf 2x8K, P^T bf16 16K (PV operand), P2 f32 32K (normalized P, swizzled),
//      colacc/mbits. 66 KB -> 2 blocks/CU.
// Pass 2 per tile: QK -> stageK(t+1) -> epilogue writes P^T(bf16) + P2(f32) to LDS
//   (NO global stores) -> PV -> row-contiguous att sweep from P2 (512B/row) -> stageV(t+1).
__global__ __launch_bounds__(256, 2) void k_att(const unsigned short* __restrict__ kt,
                                                const unsigned short* __restrict__ qt,
                                                const unsigned short* __restrict__ vbuf,
                                                const int* __restrict__ mask,
                                                float* __restrict__ att,
                                                unsigned short* __restrict__ ctxT) {
  __shared__ char lds[66176];
  constexpr int KOFF = 0, VOFF = 8192, POFF = 16384, P2OFF = 32768, COFF = 65536;
  float* colacc = (float*)(lds + COFF);                                 // 128 f32
  unsigned long long* mbits = (unsigned long long*)(lds + COFF + 512);  // 16 u64
  const int tid = threadIdx.x, lane = tid & 63, wave = tid >> 6;
  const int wr = wave >> 1, wc = wave & 1;
  const int bh = blockIdx.x, qb = blockIdx.y;   // x=bh so q-replicas share an XCD
  const int b = bh >> 4, h = bh & 15, hb = h * NB + b;
  const int q0 = qb * 128;
  const unsigned short* ktp = kt + (size_t)bh * NT * ND;
  const unsigned short* qtp = qt + ((size_t)bh * NT + q0) * ND;
  const unsigned short* vp  = vbuf + (size_t)bh * ND * NT;
  const int l15 = lane & 15, g = lane >> 4;

  if (tid < 128) colacc[tid] = 0.f;
  stage_tile<128>(qtp, ND, lds, POFF, tid);     // Q parked in P^T region
#pragma unroll
  for (int j = 0; j < 4; ++j) {
    unsigned long long bb = __ballot(mask[b * NT + wave * 256 + j * 64 + lane] != 0);
    if (lane == 0) mbits[wave * 4 + j] = bb;
  }
  i32x4 qm4[4];
#pragma unroll
  for (int nf = 0; nf < 4; ++nf)
    qm4[nf] = *(const i32x4*)(mask + b * NT + q0 + wc * 64 + nf * 16 + g * 4);
  asm volatile("s_waitcnt vmcnt(0)" ::: "memory");
  __syncthreads();   // Q + mbits resident; vmcnt exactly 0

  s16x8 qf[4][2];
#pragma unroll
  for (int nf = 0; nf < 4; ++nf)
#pragma unroll
    for (int ks = 0; ks < 2; ++ks)
      qf[nf][ks] = frag_ld(lds, POFF, wc * 64 + nf * 16 + l15, ks, lane);
  __syncthreads();   // all waves have Q in regs; P^T region reusable

  // per-thread k-mask: bit (t*2+mf) for k = t*64 + wr*32 + mf*16 + l15
  unsigned int kmask32 = 0;
#pragma unroll
  for (int t = 0; t < 16; ++t) {
    const unsigned long long w64 = mbits[t];
#pragma unroll
    for (int mf = 0; mf < 2; ++mf)
      kmask32 |= (unsigned int)((w64 >> (wr * 32 + mf * 16 + l15)) & 1ull) << (t * 2 + mf);
  }

  const float scl = 0.125f * 1.44269504f;  // scale * log2(e)

  // ---- pass 1: denominators (K dbuf KOFF/VOFF, counted vmcnt(2)) ----
  f32x4 cs4[4];
#pragma unroll
  for (int nf = 0; nf < 4; ++nf) cs4[nf] = (f32x4){0.f, 0.f, 0.f, 0.f};
  stage_tile<64>(ktp, ND, lds, KOFF, tid);
  for (int t = 0; t < 16; ++t) {
    __builtin_amdgcn_s_barrier();
    if (t < 15) {
      stage_tile<64>(ktp + (size_t)(t + 1) * 64 * ND, ND, lds, (t & 1) ? KOFF : VOFF, tid);
      asm volatile("s_waitcnt vmcnt(2)" ::: "memory");   // tile t resident
    } else {
      asm volatile("s_waitcnt vmcnt(0)" ::: "memory");
    }
    __builtin_amdgcn_s_barrier();
    const int koff = (t & 1) ? VOFF : KOFF;
    f32x4 sacc[2][4];
#pragma unroll
    for (int i = 0; i < 2; ++i)
#pragma unroll
      for (int j = 0; j < 4; ++j) sacc[i][j] = (f32x4){0.f, 0.f, 0.f, 0.f};
#pragma unroll
    for (int ks = 0; ks < 2; ++ks) {
      s16x8 kf[2];
#pragma unroll
      for (int mf = 0; mf < 2; ++mf)
        kf[mf] = frag_ld(lds, koff, wr * 32 + mf * 16 + l15, ks, lane);
#pragma unroll
      for (int mf = 0; mf < 2; ++mf)
#pragma unroll
        for (int nf = 0; nf < 4; ++nf)
          sacc[mf][nf] = __builtin_amdgcn_mfma_f32_16x16x32_bf16(qf[nf][ks], kf[mf], sacc[mf][nf], 0, 0, 0);
    }
#pragma unroll
    for (int mf = 0; mf < 2; ++mf) {
      const float kz = ((kmask32 >> (t * 2 + mf)) & 1u) ? 0.f : 1.f;
#pragma unroll
      for (int nf = 0; nf < 4; ++nf)
#pragma unroll
        for (int i = 0; i < 4; ++i)
          cs4[nf][i] += kz * fexp2(sacc[mf][nf][i] * scl);
    }
  }
  // reduce over 16 lanes (k) per group, then atomic-combine wr halves
#pragma unroll
  for (int nf = 0; nf < 4; ++nf)
#pragma unroll
    for (int i = 0; i < 4; ++i) {
      float v = cs4[nf][i];
      v += __shfl_xor(v, 1); v += __shfl_xor(v, 2);
      v += __shfl_xor(v, 4); v += __shfl_xor(v, 8);
      cs4[nf][i] = v;
    }
  if (l15 == 0) {
#pragma unroll
    for (int nf = 0; nf < 4; ++nf)
#pragma unroll
      for (int i = 0; i < 4; ++i)
        atomicAdd(&colacc[wc * 64 + nf * 16 + g * 4 + i], cs4[nf][i]);
  }
  __syncthreads();
  f32x4 sq4[4];
#pragma unroll
  for (int nf = 0; nf < 4; ++nf)
#pragma unroll
    for (int i = 0; i < 4; ++i)
      sq4[nf][i] = qm4[nf][i] ? 0.f : 1.0f / colacc[wc * 64 + nf * 16 + g * 4 + i];

  // ---- pass 2: QK -> P^T+P2 relay -> PV -> row-contiguous att sweep ----
  f32x4 cacc[4][2];
#pragma unroll
  for (int i = 0; i < 4; ++i)
#pragma unroll
    for (int j = 0; j < 2; ++j) cacc[i][j] = (f32x4){0.f, 0.f, 0.f, 0.f};

  stage_tile<64>(ktp, ND, lds, KOFF, tid);       // 2 ops
  stage_tile<64>(vp, NT, lds, VOFF, tid);        // 2 ops (V rows d, stride NT)
  asm volatile("s_waitcnt vmcnt(0)" ::: "memory");
  __builtin_amdgcn_s_barrier();

  float* attbase = att + (size_t)hb * NT * NT + q0;
  const int swj = lane & 31, rsel = lane >> 5;
  for (int t = 0; t < 16; ++t) {
    // QK(t) reads KOFF
    f32x4 sacc[2][4];
#pragma unroll
    for (int i = 0; i < 2; ++i)
#pragma unroll
      for (int j = 0; j < 4; ++j) sacc[i][j] = (f32x4){0.f, 0.f, 0.f, 0.f};
#pragma unroll
    for (int ks = 0; ks < 2; ++ks) {
      s16x8 kf[2];
#pragma unroll
      for (int mf = 0; mf < 2; ++mf)
        kf[mf] = frag_ld(lds, KOFF, wr * 32 + mf * 16 + l15, ks, lane);
#pragma unroll
      for (int mf = 0; mf < 2; ++mf)
#pragma unroll
        for (int nf = 0; nf < 4; ++nf)
          sacc[mf][nf] = __builtin_amdgcn_mfma_f32_16x16x32_bf16(qf[nf][ks], kf[mf], sacc[mf][nf], 0, 0, 0);
    }
    __builtin_amdgcn_s_barrier();                 // KOFF free
    if (t < 15) stage_tile<64>(ktp + (size_t)(t + 1) * 64 * ND, ND, lds, KOFF, tid);  // 2 ops
    __builtin_amdgcn_sched_barrier(0);            // pin: stageK before LDS work

    // epilogue: p4 = kz * exp * sq -> P^T (bf16, PV operand) + P2 (f32, att staging)
#pragma unroll
    for (int mf = 0; mf < 2; ++mf) {
      const float kz = ((kmask32 >> (t * 2 + mf)) & 1u) ? 0.f : 1.f;
      const int kloc = wr * 32 + mf * 16 + l15;
#pragma unroll
      for (int nf = 0; nf < 4; ++nf) {
        f32x4 p4;
#pragma unroll
        for (int i = 0; i < 4; ++i)
          p4[i] = kz * fexp2(sacc[mf][nf][i] * scl) * sq4[nf][i];
        const int qrow = wc * 64 + nf * 16 + g * 4;
#pragma unroll
        for (int i = 0; i < 4; ++i) {
          const int row = qrow + i;
          *(unsigned short*)(lds + POFF + row * 128 + (((kloc >> 3) ^ (row & 7)) << 4)
                             + ((kloc & 7) << 1)) = cvt_bf16(p4[i]);
        }
        // P2[kloc][q-chunk]: chunk q4 = qrow>>2, swizzled by kloc&7 (~2-way conflicts)
        const int q4 = wc * 16 + nf * 4 + g;
        *(f32x4*)(lds + P2OFF + kloc * 512 + ((q4 ^ (kloc & 7)) << 4)) = p4;
      }
    }
    asm volatile("s_waitcnt lgkmcnt(0)" ::: "memory");  // P^T + P2 visible
    __builtin_amdgcn_sched_barrier(0);
    __builtin_amdgcn_s_barrier();
    // V(t) resident: FIFO holds [stores(t-1) (old), stageK(t+1) 2] -> keep only stageK
    if (t < 15) asm volatile("s_waitcnt vmcnt(2)" ::: "memory");
    else        asm volatile("s_waitcnt vmcnt(0)" ::: "memory");

    // PV(t): ctx[d][q] += V[d][k] * P[k][q]
#pragma unroll
    for (int ks2 = 0; ks2 < 2; ++ks2) {
      s16x8 vf[4], pf[2];
#pragma unroll
      for (int mf = 0; mf < 4; ++mf)
        vf[mf] = frag_ld(lds, VOFF, mf * 16 + l15, ks2, lane);
#pragma unroll
      for (int nf2 = 0; nf2 < 2; ++nf2)
        pf[nf2] = frag_ld(lds, POFF, wave * 32 + nf2 * 16 + l15, ks2, lane);
#pragma unroll
      for (int mf = 0; mf < 4; ++mf)
#pragma unroll
        for (int nf2 = 0; nf2 < 2; ++nf2)
          cacc[mf][nf2] = __builtin_amdgcn_mfma_f32_16x16x32_bf16(vf[mf], pf[nf2], cacc[mf][nf2], 0, 0, 0);
    }
    __builtin_amdgcn_s_barrier();                 // VOFF free; P2 complete for sweep

    // att sweep tile t: row-contiguous 512B stores from P2 (conflict-free reads)
    {
      float* attrow = attbase + (size_t)(t * 64) * NT;
#pragma unroll
      for (int r = 0; r < 8; ++r) {
        const int kk = wave * 16 + r * 2 + rsel;
        const f32x4 pv4 = *(const f32x4*)(lds + P2OFF + kk * 512 + ((swj ^ (kk & 7)) << 4));
        __builtin_nontemporal_store(pv4, (f32x4*)(attrow + (size_t)kk * NT + swj * 4));
      }
    }
    if (t < 15) {
      stage_tile<64>(vp + (t + 1) * 64, NT, lds, VOFF, tid);   // 2 ops
      // K(t+1) resident: FIFO [stageK(t+1) 2, stores(t) 8, stageV(t+1) 2] -> keep 10
      asm volatile("s_waitcnt vmcnt(10)" ::: "memory");
      __builtin_amdgcn_s_barrier();               // also fences sweep reads vs next P2 write
    }
  }

  // ctx epilogue: ctxT[b][q][h*64+d]
#pragma unroll
  for (int mf = 0; mf < 4; ++mf) {
    const int d0 = mf * 16 + (g << 2);
#pragma unroll
    for (int nf2 = 0; nf2 < 2; ++nf2) {
      const int q = q0 + wave * 32 + nf2 * 16 + l15;
      u16x4 v4;
#pragma unroll
      for (int i = 0; i < 4; ++i) v4[i] = cvt_bf16(cacc[mf][nf2][i]);
      *(u16x4*)(ctxT + ((size_t)b * NT + q) * NC + h * ND + d0) = v4;
    }
  }
}

// ---------------- out-projection + residual + GN partial sums (128², full chip) ----------------
__global__ __launch_bounds__(256) void k_outgemm(const unsigned short* __restrict__ Wo,
                                                 const unsigned short* __restrict__ ctxT,
                                                 const float* __restrict__ x,
                                                 float* __restrict__ y0,
                                                 float* __restrict__ partials) {
  __shared__ char lds[32832];
  const int tid = threadIdx.x, lane = tid & 63, wave = tid >> 6;
  const int wr = wave >> 1, wc = wave & 1;
  const int bm = blockIdx.x, bn = blockIdx.y, b = blockIdx.z;
  const unsigned short* A = Wo + (size_t)bm * 128 * NC;
  const unsigned short* Bt = ctxT + ((size_t)b * NT + (size_t)bn * 128) * NC;
  f32x4 acc[4][4];
  gemm_core_128<NC>(A, Bt, NC, NC, lds, tid, acc);

  float lsum = 0.f, lsq = 0.f;
#pragma unroll
  for (int mf = 0; mf < 4; ++mf) {
#pragma unroll
    for (int nf = 0; nf < 4; ++nf) {
      const int gc = bn * 128 + wc * 64 + nf * 16 + (lane & 15);
#pragma unroll
      for (int i = 0; i < 4; ++i) {
        const int gr = bm * 128 + wr * 64 + mf * 16 + ((lane >> 4) << 2) + i;
        const size_t idx = ((size_t)b * NC + gr) * NT + gc;
        const float v = acc[mf][nf][i] + x[idx];
        y0[idx] = v;
        lsum += v; lsq += v * v;
      }
    }
  }
#pragma unroll
  for (int off = 32; off; off >>= 1) {
    lsum += __shfl_xor(lsum, off);
    lsq += __shfl_xor(lsq, off);
  }
  __syncthreads();
  float* red = (float*)(lds + 32768);
  if (lane == 0) { red[wave * 2] = lsum; red[wave * 2 + 1] = lsq; }
  __syncthreads();
  if (tid == 0) {
    const float s = red[0] + red[2] + red[4] + red[6];
    const float qq = red[1] + red[3] + red[5] + red[7];
    const int bi = bm * 8 + bn;
    partials[((size_t)b * 64 + bi) * 2] = s;
    partials[((size_t)b * 64 + bi) * 2 + 1] = qq;
  }
}

__global__ void k_gnstats(const float* __restrict__ partials, float* __restrict__ gnp) {
  const int b = blockIdx.x, t = threadIdx.x;
  float s = partials[((size_t)b * 64 + t) * 2];
  float q = partials[((size_t)b * 64 + t) * 2 + 1];
#pragma unroll
  for (int off = 32; off; off >>= 1) {
    s += __shfl_xor(s, off);
    q += __shfl_xor(q, off);
  }
  if (t == 0) {
    const float n = 1048576.f;
    const float mean = s / n;
    const float var = q / n - mean * mean;
    gnp[b * 2] = mean;
    gnp[b * 2 + 1] = rsqrtf(var + 1e-5f);
  }
}

__global__ __launch_bounds__(256) void k_gnapply(const float* __restrict__ y0,
                                                 const float* __restrict__ gnp,
                                                 const float* __restrict__ gw,
                                                 const float* __restrict__ gb,
                                                 float* __restrict__ out) {
  const size_t n4 = (size_t)NB * NC * NT / 4;
  const size_t stride = (size_t)gridDim.x * blockDim.x;
  for (size_t i = (size_t)blockIdx.x * blockDim.x + threadIdx.x; i < n4; i += stride) {
    const size_t base = i * 4;
    const int b = (int)(base >> 20);
    const int c = (int)((base >> 10) & 1023);
    const f32x4 v = *(const f32x4*)(y0 + base);
    const float m = gnp[b * 2], r = gnp[b * 2 + 1];
    const float sw = gw[c] * r, sb = gb[c];
    f32x4 o;
#pragma unroll
    for (int j = 0; j < 4; ++j) o[j] = (v[j] - m) * sw + sb;
    *(f32x4*)(out + base) = o;
  }
}

extern "C" void kernel_launch(void* const* d_in, const int* in_sizes, int n_in,
                              void* d_out, int out_size, void* d_ws, size_t ws_size,
                              hipStream_t stream) {
  (void)in_sizes; (void)n_in; (void)out_size; (void)ws_size;
  const float* x     = (const float*)d_in[0];
  const int*   mask  = (const int*)d_in[1];
  const float* w_kvq = (const float*)d_in[2];
  const float* w_out = (const float*)d_in[3];
  const float* gnw   = (const float*)d_in[4];
  const float* gnb   = (const float*)d_in[5];
  float* outy = (float*)d_out;
  float* att  = outy + (size_t)NB * NC * NT;  // att_ret region of d_out

  char* ws = (char*)d_ws;
  unsigned short* wkvq_bf = (unsigned short*)(ws);             //  6,291,456 B
  unsigned short* wout_bf = (unsigned short*)(ws + 6291456);   //  2,097,152 B
  unsigned short* xT      = (unsigned short*)(ws + 8388608);   // 16,777,216 B
  unsigned short* ctxT    = xT;                                // alias: xT dead after gemm1
  unsigned short* kt      = (unsigned short*)(ws + 25165824);  // 16,777,216 B
  unsigned short* qt      = (unsigned short*)(ws + 41943040);  // 16,777,216 B
  float*          y0      = (float*)(ws + 25165824);           // alias kt+qt: dead after att
  unsigned short* vbuf    = (unsigned short*)(ws + 58720256);  // 16,777,216 B
  float*          part    = (float*)(ws + 76021760);           //      4,096 B
  float*          gnp     = (float*)(ws + 76025856);           //         64 B

  k_prep<<<2048, 256, 0, stream>>>(w_kvq, wkvq_bf, w_out, wout_bf);
  k_xT<<<dim3(32, 32, 8), dim3(32, 8), 0, stream>>>(x, xT);
  k_gemm1_256<<<384, 512, 0, stream>>>(wkvq_bf, xT, kt, qt, vbuf);
  k_att<<<dim3(128, 8), 256, 0, stream>>>(kt, qt, vbuf, mask, att, ctxT);
  k_outgemm<<<dim3(8, 8, 8), 256, 0, stream>>>(wout_bf, ctxT, x, y0, part);
  k_gnstats<<<8, 64, 0, stream>>>(part, gnp);
  k_gnapply<<<4096, 256, 0, stream>>>(y0, gnp, gnw, gnb, outy);
}